// Round 1
// baseline (1066.802 us; speedup 1.0000x reference)
//
#include <hip/hip_runtime.h>
#include <math.h>

// Problem dims (fixed by reference)
#define S_ 4096
#define B_ 4
#define D_ 1024
#define R_ (S_*B_)   // 16384 rows
#define H_ (4*D_)    // 4096

typedef unsigned short u16;
typedef unsigned int   u32;
typedef __attribute__((ext_vector_type(8))) short bf16x8;  // 8 bf16 in 4 VGPRs
typedef __attribute__((ext_vector_type(4))) float f32x4;

__device__ __forceinline__ u16 f2bf(float f) {
  u32 u = __float_as_uint(f);
  u32 r = (u + 0x7fffu + ((u >> 16) & 1u)) >> 16;   // RNE
  return (u16)r;
}
__device__ __forceinline__ float bf2f(u16 u) {
  return __uint_as_float(((u32)u) << 16);
}

// async global->LDS, 16B per lane; LDS dest is wave-uniform base + lane*16
__device__ __forceinline__ void gl_lds16(const u16* g, u16* l) {
  __builtin_amdgcn_global_load_lds((const __attribute__((address_space(1))) void*)g,
                                   (__attribute__((address_space(3))) void*)l,
                                   16, 0, 0);
}

// ---------------------------------------------------------------------------
// fp32 -> bf16 convert (vector x4)
__global__ __launch_bounds__(256) void f2bf_k(const float* __restrict__ in,
                                              u16* __restrict__ out, int n4) {
  int i = blockIdx.x * 256 + threadIdx.x;
  if (i < n4) {
    float4 v = ((const float4*)in)[i];
    u16 o0 = f2bf(v.x), o1 = f2bf(v.y), o2 = f2bf(v.z), o3 = f2bf(v.w);
    ushort4 o = make_ushort4(o0, o1, o2, o3);
    ((ushort4*)out)[i] = o;
  }
}

// ---------------------------------------------------------------------------
// LayerNorm over D=1024, one row per 256-thread block, 4 elems/thread.
// TR=true: input row r=(s*B+b) of x[S,B,D] -> output row (b*S+s)  (the [B,S,D] transpose)
// TR=false: same row index in and out.
template<bool TR>
__global__ __launch_bounds__(256) void ln_k(const float* __restrict__ x,
                                            u16* __restrict__ o,
                                            const float* __restrict__ g,
                                            const float* __restrict__ bb) {
  const int row = blockIdx.x;
  const int tid = threadIdx.x;
  const float4 v = *(const float4*)&x[(long)row * D_ + tid * 4];
  float vv[4] = {v.x, v.y, v.z, v.w};
  float s = vv[0] + vv[1] + vv[2] + vv[3];
  float q = vv[0]*vv[0] + vv[1]*vv[1] + vv[2]*vv[2] + vv[3]*vv[3];
  const int l = tid & 63, w = tid >> 6;
  #pragma unroll
  for (int off = 32; off > 0; off >>= 1) {
    s += __shfl_down(s, off, 64);
    q += __shfl_down(q, off, 64);
  }
  __shared__ float red[8];
  if (l == 0) { red[w] = s; red[4 + w] = q; }
  __syncthreads();
  s = red[0] + red[1] + red[2] + red[3];
  q = red[4] + red[5] + red[6] + red[7];
  const float m   = s * (1.0f / D_);
  const float var = q * (1.0f / D_) - m * m;
  const float inv = rsqrtf(var + 1e-5f);
  const long orow = TR ? ((long)(row % B_) * S_ + (row / B_)) : (long)row;
  const int j = tid * 4;
  ushort4 ou = make_ushort4(
      f2bf((vv[0] - m) * inv * g[j+0] + bb[j+0]),
      f2bf((vv[1] - m) * inv * g[j+1] + bb[j+1]),
      f2bf((vv[2] - m) * inv * g[j+2] + bb[j+2]),
      f2bf((vv[3] - m) * inv * g[j+3] + bb[j+3]));
  *(ushort4*)&o[orow * D_ + j] = ou;
}

// ---------------------------------------------------------------------------
// column sums of XWv (for the ones(n,n)/n term): first[b][d] += sum_n XWv[b][n][d]
// grid (D/256, 16, B); each block sums 256 rows, atomicAdd partials.
__global__ __launch_bounds__(256) void colsum_k(const u16* __restrict__ Xw,
                                                float* __restrict__ first) {
  const int d  = blockIdx.x * 256 + threadIdx.x;
  const int b  = blockIdx.z;
  const int n0 = blockIdx.y * 256;
  const u16* p = Xw + ((long)b * S_ + n0) * D_ + d;
  float s = 0.f;
  #pragma unroll 8
  for (int n = 0; n < 256; ++n) s += bf2f(p[(long)n * D_]);
  atomicAdd(&first[b * D_ + d], s);
}

// ---------------------------------------------------------------------------
// Tiled bf16 MFMA GEMM, 128x128 tile, BK=32, 256 threads = 4 waves (2x2),
// each wave a 64x64 sub-tile as 4x4 frags of 16x16x32 MFMA.
//
// TRANS=false (NT):  C[i,j] = sum_k A[i*K+k] * B[j*K+k]        (lda=ldb=K)
// TRANS=true  (TN):  C[i,j] = sum_k A[k*D_+i] * B[k*D_+j]      (K rows, D_ cols)
//
// EPI 0: Cb[bz*sCz + i*ldc + j] = bf16(acc)
// EPI 1: (attn epilogue) Cf[(i*B_+bz)*D_ + j] = X[i,j] + first[bz,j]/S + scale*acc
// EPI 2: Cb[i*ldc + j] = bf16(gelu(acc + vec1[j]))
// EPI 3: Cf[i*ldc + j] += acc + vec1[j]
template<int EPI, bool TRANS>
__global__ __launch_bounds__(256, 2) void gemm_k(
    const u16* __restrict__ A, long sAz,
    const u16* __restrict__ B, long sBz,
    int K, int ldc,
    u16* __restrict__ Cb, long sCz,
    float* __restrict__ Cf,
    const float* __restrict__ vec1,
    float scale)
{
  const int bz = blockIdx.z;
  const u16* Ab = A + (long)bz * sAz;
  const u16* Bb = B + (long)bz * sBz;
  const int row0 = blockIdx.x * 128;
  const int col0 = blockIdx.y * 128;
  const int lda = TRANS ? D_ : K;

  __shared__ __align__(16) u16 As[128 * 32];
  __shared__ __align__(16) u16 Bs[128 * 32];

  const int tid = threadIdx.x;
  const int w = tid >> 6;
  const int l = tid & 63;
  const int wr = (w >> 1) * 64;   // wave row offset in tile
  const int wc = (w & 1) * 64;    // wave col offset in tile

  f32x4 acc[4][4];
  #pragma unroll
  for (int mi = 0; mi < 4; ++mi)
    #pragma unroll
    for (int ni = 0; ni < 4; ++ni) acc[mi][ni] = (f32x4){0.f, 0.f, 0.f, 0.f};

  const int lrow = l & 15;          // m (A-frag) / n (B-frag) lane index
  const int kblk = (l >> 4) << 3;   // k sub-block: 0,8,16,24

  for (int k0 = 0; k0 < K; k0 += 32) {
    __syncthreads();                 // protect LDS from previous iter's readers
    if constexpr (!TRANS) {
      // direct global->LDS: tile rows contiguous along K, LDS [128][32] linear
      #pragma unroll
      for (int it = 0; it < 2; ++it) {
        const int cb = it * 256 + (w << 6);   // wave-uniform chunk base
        const int c  = cb + l;                // this lane's 16B chunk
        const int r  = c >> 2;                // tile row
        const int co = (c & 3) << 3;          // k-offset (elements)
        gl_lds16(Ab + (long)(row0 + r) * lda + (k0 + co), &As[cb << 3]);
        gl_lds16(Bb + (long)(col0 + r) * lda + (k0 + co), &Bs[cb << 3]);
      }
    } else {
      // TN: global tile is [32 k-rows][128 cols]; stage transposed into [128][32]
      #pragma unroll
      for (int it = 0; it < 2; ++it) {
        const int c  = it * 256 + tid;
        const int kk = c >> 4;                // k row 0..31
        const int co = (c & 15) << 3;         // col offset 0..120
        bf16x8 ga = *(const bf16x8*)(Ab + (long)(k0 + kk) * lda + row0 + co);
        bf16x8 gb = *(const bf16x8*)(Bb + (long)(k0 + kk) * lda + col0 + co);
        #pragma unroll
        for (int u = 0; u < 8; ++u) {
          As[(co + u) * 32 + kk] = (u16)ga[u];
          Bs[(co + u) * 32 + kk] = (u16)gb[u];
        }
      }
    }
    __syncthreads();

    bf16x8 af[4], bfr[4];
    #pragma unroll
    for (int mi = 0; mi < 4; ++mi)
      af[mi]  = *(const bf16x8*)&As[(wr + mi * 16 + lrow) * 32 + kblk];
    #pragma unroll
    for (int ni = 0; ni < 4; ++ni)
      bfr[ni] = *(const bf16x8*)&Bs[(wc + ni * 16 + lrow) * 32 + kblk];
    #pragma unroll
    for (int mi = 0; mi < 4; ++mi)
      #pragma unroll
      for (int ni = 0; ni < 4; ++ni)
        acc[mi][ni] = __builtin_amdgcn_mfma_f32_16x16x32_bf16(af[mi], bfr[ni], acc[mi][ni], 0, 0, 0);
  }

  // epilogue: C/D frag mapping col=lane&15, row=(lane>>4)*4+reg
  const int rbase = row0 + wr + ((l >> 4) << 2);
  const int cbase = col0 + wc + (l & 15);
  #pragma unroll
  for (int mi = 0; mi < 4; ++mi) {
    #pragma unroll
    for (int ni = 0; ni < 4; ++ni) {
      #pragma unroll
      for (int r = 0; r < 4; ++r) {
        const int i = rbase + mi * 16 + r;
        const int j = cbase + ni * 16;
        const float a = acc[mi][ni][r];
        if constexpr (EPI == 0) {
          Cb[(long)bz * sCz + (long)i * ldc + j] = f2bf(a);
        } else if constexpr (EPI == 1) {
          // h[s=i, b=bz, j] = X + first/n + scale*second  (written fp32 to d_out)
          const float xv = bf2f(Ab[(long)i * K + j]);   // K == D_ here
          Cf[((long)i * B_ + bz) * (long)D_ + j] =
              xv + vec1[bz * D_ + j] * (1.0f / S_) + scale * a;
        } else if constexpr (EPI == 2) {
          const float t = a + vec1[j];
          const float ge = 0.5f * t * (1.0f + erff(t * 0.70710678118654752f));
          Cb[(long)i * ldc + j] = f2bf(ge);
        } else {
          const long idx = (long)i * ldc + j;
          Cf[idx] = Cf[idx] + a + vec1[j];
        }
      }
    }
  }
}

// ---------------------------------------------------------------------------
extern "C" void kernel_launch(void* const* d_in, const int* in_sizes, int n_in,
                              void* d_out, int out_size, void* d_ws, size_t ws_size,
                              hipStream_t stream) {
  (void)in_sizes; (void)n_in; (void)out_size; (void)ws_size;
  const float* x     = (const float*)d_in[0];
  const float* W_v   = (const float*)d_in[1];
  const float* theta = (const float*)d_in[2];
  const float* ln1g  = (const float*)d_in[3];
  const float* ln1b  = (const float*)d_in[4];
  const float* ln2g  = (const float*)d_in[5];
  const float* ln2b  = (const float*)d_in[6];
  const float* w1    = (const float*)d_in[7];
  const float* b1    = (const float*)d_in[8];
  const float* w2    = (const float*)d_in[9];
  const float* b2    = (const float*)d_in[10];
  float* out = (float*)d_out;

  char* ws = (char*)d_ws;
  const size_t MB = 1024ull * 1024ull;
  u16*   Wv_bf = (u16*)(ws + 0);          //  2 MB
  u16*   Th_bf = (u16*)(ws + 2 * MB);     //  2 MB
  u16*   w1_bf = (u16*)(ws + 4 * MB);     //  8 MB
  u16*   w2_bf = (u16*)(ws + 12 * MB);    //  8 MB
  float* first = (float*)(ws + 20 * MB);  // 16 KB (B*D f32)
  u16*   Xn    = (u16*)(ws + 24 * MB);    // 32 MB  [B][S][D] bf16 (LN1 out, transposed)
  u16*   XWv   = (u16*)(ws + 56 * MB);    // 32 MB
  u16*   Xth   = (u16*)(ws + 88 * MB);    // 32 MB
  u16*   Mt    = (u16*)(ws + 120 * MB);   //  8 MB  Mt[b][e][d] = M[b][d][e]
  u16*   h2    = (u16*)(ws + 128 * MB);   // 32 MB  LN2 out bf16
  u16*   G     = (u16*)(ws + 160 * MB);   // 32 MB  gelu chunk [4096][4096] bf16

  // 1) weights -> bf16
  f2bf_k<<<dim3((D_*D_/4 + 255)/256), 256, 0, stream>>>(W_v,   Wv_bf, D_*D_/4);
  f2bf_k<<<dim3((D_*D_/4 + 255)/256), 256, 0, stream>>>(theta, Th_bf, D_*D_/4);
  f2bf_k<<<dim3((H_*D_/4 + 255)/256), 256, 0, stream>>>(w1,    w1_bf, H_*D_/4);
  f2bf_k<<<dim3((H_*D_/4 + 255)/256), 256, 0, stream>>>(w2,    w2_bf, H_*D_/4);

  // 2) LN1 + transpose to [B][S][D]
  ln_k<true><<<dim3(R_), 256, 0, stream>>>(x, Xn, ln1g, ln1b);

  // 3) XWv = Xn @ W_v^T   (M=16384, N=1024, K=1024)
  gemm_k<0,false><<<dim3(R_/128, D_/128, 1), 256, 0, stream>>>(
      Xn, 0, Wv_bf, 0, D_, D_, XWv, 0, nullptr, nullptr, 0.f);
  // 4) Xth = Xn @ theta^T
  gemm_k<0,false><<<dim3(R_/128, D_/128, 1), 256, 0, stream>>>(
      Xn, 0, Th_bf, 0, D_, D_, Xth, 0, nullptr, nullptr, 0.f);

  // 5) first[b][d] = sum_n XWv[b][n][d]
  hipMemsetAsync(first, 0, B_ * D_ * sizeof(float), stream);
  colsum_k<<<dim3(D_/256, 16, B_), 256, 0, stream>>>(XWv, first);

  // 6) Mt[b][e][d] = sum_n XWv[b][n][e] * Xth[b][n][d]   (TN, K=4096, per batch)
  gemm_k<0,true><<<dim3(D_/128, D_/128, B_), 256, 0, stream>>>(
      XWv, (long)S_*D_, Xth, (long)S_*D_, S_, D_, Mt, (long)D_*D_, nullptr, nullptr, 0.f);

  // 7) h = X + first/n + (1/(n*sqrt(D))) * Xn @ Mt^T   -> d_out fp32 [S][B][D]
  gemm_k<1,false><<<dim3(S_/128, D_/128, B_), 256, 0, stream>>>(
      Xn, (long)S_*D_, Mt, (long)D_*D_, D_, D_, nullptr, 0, out, first,
      1.0f / ((float)S_ * 32.0f));

  // 8) LN2: d_out -> h2 (bf16)
  ln_k<false><<<dim3(R_), 256, 0, stream>>>(out, h2, ln2g, ln2b);

  // 9) MLP in 4 row-chunks of 4096 rows (G buffer reuse keeps ws small)
  for (int c = 0; c < 4; ++c) {
    const long ro = (long)c * 4096;
    // G = gelu(h2 @ w1^T + b1)   (M=4096, N=4096, K=1024)
    gemm_k<2,false><<<dim3(32, H_/128, 1), 256, 0, stream>>>(
        h2 + ro * D_, 0, w1_bf, 0, D_, H_, G, 0, nullptr, b1, 0.f);
    // out += G @ w2^T + b2       (M=4096, N=1024, K=4096)
    gemm_k<3,false><<<dim3(32, D_/128, 1), 256, 0, stream>>>(
        G, 0, w2_bf, 0, H_, D_, nullptr, 0, out + ro * D_, b2, 0.f);
  }
}

// Round 2
// 733.235 us; speedup vs baseline: 1.4549x; 1.4549x over previous
//
#include <hip/hip_runtime.h>
#include <math.h>

// Problem dims (fixed by reference)
#define S_ 4096
#define B_ 4
#define D_ 1024
#define R_ (S_*B_)   // 16384 rows
#define H_ (4*D_)    // 4096

typedef unsigned short u16;
typedef unsigned int   u32;
typedef __attribute__((ext_vector_type(8))) short bf16x8;  // 8 bf16 in 4 VGPRs
typedef __attribute__((ext_vector_type(4))) float f32x4;

__device__ __forceinline__ u16 f2bf(float f) {
  u32 u = __float_as_uint(f);
  u32 r = (u + 0x7fffu + ((u >> 16) & 1u)) >> 16;   // RNE
  return (u16)r;
}
__device__ __forceinline__ float bf2f(u16 u) {
  return __uint_as_float(((u32)u) << 16);
}

// async global->LDS, 16B per lane; LDS dest is wave-uniform base + lane*16
__device__ __forceinline__ void gl_lds16(const u16* g, u16* l) {
  __builtin_amdgcn_global_load_lds((const __attribute__((address_space(1))) void*)g,
                                   (__attribute__((address_space(3))) void*)l,
                                   16, 0, 0);
}

// ---------------------------------------------------------------------------
// fp32 -> bf16 convert (vector x4)
__global__ __launch_bounds__(256) void f2bf_k(const float* __restrict__ in,
                                              u16* __restrict__ out, int n4) {
  int i = blockIdx.x * 256 + threadIdx.x;
  if (i < n4) {
    float4 v = ((const float4*)in)[i];
    ushort4 o = make_ushort4(f2bf(v.x), f2bf(v.y), f2bf(v.z), f2bf(v.w));
    ((ushort4*)out)[i] = o;
  }
}

// ---------------------------------------------------------------------------
// LayerNorm over D=1024, one row per 256-thread block, 4 elems/thread.
// TR=true: input row r=(s*B+b) of x[S,B,D] -> output row (b*S+s)
template<bool TR>
__global__ __launch_bounds__(256) void ln_k(const float* __restrict__ x,
                                            u16* __restrict__ o,
                                            const float* __restrict__ g,
                                            const float* __restrict__ bb) {
  const int row = blockIdx.x;
  const int tid = threadIdx.x;
  const float4 v = *(const float4*)&x[(long)row * D_ + tid * 4];
  float vv[4] = {v.x, v.y, v.z, v.w};
  float s = vv[0] + vv[1] + vv[2] + vv[3];
  float q = vv[0]*vv[0] + vv[1]*vv[1] + vv[2]*vv[2] + vv[3]*vv[3];
  const int l = tid & 63, w = tid >> 6;
  #pragma unroll
  for (int off = 32; off > 0; off >>= 1) {
    s += __shfl_down(s, off, 64);
    q += __shfl_down(q, off, 64);
  }
  __shared__ float red[8];
  if (l == 0) { red[w] = s; red[4 + w] = q; }
  __syncthreads();
  s = red[0] + red[1] + red[2] + red[3];
  q = red[4] + red[5] + red[6] + red[7];
  const float m   = s * (1.0f / D_);
  const float var = q * (1.0f / D_) - m * m;
  const float inv = rsqrtf(var + 1e-5f);
  const long orow = TR ? ((long)(row % B_) * S_ + (row / B_)) : (long)row;
  const int j = tid * 4;
  ushort4 ou = make_ushort4(
      f2bf((vv[0] - m) * inv * g[j+0] + bb[j+0]),
      f2bf((vv[1] - m) * inv * g[j+1] + bb[j+1]),
      f2bf((vv[2] - m) * inv * g[j+2] + bb[j+2]),
      f2bf((vv[3] - m) * inv * g[j+3] + bb[j+3]));
  *(ushort4*)&o[orow * D_ + j] = ou;
}

// ---------------------------------------------------------------------------
// column sums of XWv: first[b][d] = sum_n XWv[b][n][d]
__global__ __launch_bounds__(256) void colsum_k(const u16* __restrict__ Xw,
                                                float* __restrict__ first) {
  const int d  = blockIdx.x * 256 + threadIdx.x;
  const int b  = blockIdx.z;
  const int n0 = blockIdx.y * 256;
  const u16* p = Xw + ((long)b * S_ + n0) * D_ + d;
  float s = 0.f;
  #pragma unroll 8
  for (int n = 0; n < 256; ++n) s += bf2f(p[(long)n * D_]);
  atomicAdd(&first[b * D_ + d], s);
}

// ---------------------------------------------------------------------------
// 64x64 bf16 transpose: in [b][S_][D_] -> out [b][D_][S_]
// grid (D_/64, S_/64, B_), 256 threads. LDS stride 65 (odd) => conflict-light.
__global__ __launch_bounds__(256) void tr_k(const u16* __restrict__ in,
                                            u16* __restrict__ out) {
  __shared__ u16 t[64][65];
  const int b  = blockIdx.z;
  const int e0 = blockIdx.x * 64;
  const int n0 = blockIdx.y * 64;
  const int tid = threadIdx.x;
  #pragma unroll
  for (int i = 0; i < 4; ++i) {
    const int v = i * 256 + tid;
    const int r = v >> 4;            // n-offset 0..63
    const int c = (v & 15) << 2;     // e-offset 0,4,..,60
    ushort4 d4 = *(const ushort4*)&in[((long)b * S_ + n0 + r) * D_ + e0 + c];
    t[r][c+0] = d4.x; t[r][c+1] = d4.y; t[r][c+2] = d4.z; t[r][c+3] = d4.w;
  }
  __syncthreads();
  #pragma unroll
  for (int i = 0; i < 4; ++i) {
    const int v = i * 256 + tid;
    const int e = v >> 4;            // out row (e) 0..63
    const int c = (v & 15) << 2;     // n-offset 0,4,..,60
    ushort4 o4 = make_ushort4(t[c+0][e], t[c+1][e], t[c+2][e], t[c+3][e]);
    *(ushort4*)&out[((long)b * D_ + e0 + e) * S_ + n0 + c] = o4;
  }
}

// ---------------------------------------------------------------------------
// Tiled bf16 MFMA NT GEMM, 128x128 tile, BK=32, 256 threads = 4 waves (2x2),
// each wave a 64x64 sub-tile as 4x4 frags of 16x16x32 MFMA.
// C[i,j] = sum_k A[i*lda+k] * B[j*lda+k],  lda == K.
// LDS tiles [128][32] linear (for global_load_lds) with XOR chunk swizzle:
// LDS chunk (r,q) holds global chunk (r, q^(r&3)); frag reads apply same XOR.
//
// EPI 0: Cb[bz*sCz + i*ldc + j] = bf16(acc)
// EPI 1: Cf[(i*B_+bz)*D_ + j] = Xn[i,j] + first[bz,j]/S + scale*acc
// EPI 2: Cb[i*ldc + j] = bf16(gelu(acc + vec1[j]))
// EPI 3: Cf[i*ldc + j] += acc + vec1[j]
template<int EPI>
__global__ __launch_bounds__(256, 2) void gemm_k(
    const u16* __restrict__ A, long sAz,
    const u16* __restrict__ B, long sBz,
    int K, int ldc,
    u16* __restrict__ Cb, long sCz,
    float* __restrict__ Cf,
    const float* __restrict__ vec1,
    float scale)
{
  const int bz = blockIdx.z;
  const u16* Ab = A + (long)bz * sAz;
  const u16* Bb = B + (long)bz * sBz;
  const int row0 = blockIdx.x * 128;
  const int col0 = blockIdx.y * 128;
  const int lda = K;

  __shared__ __align__(16) u16 As[128 * 32];
  __shared__ __align__(16) u16 Bs[128 * 32];

  const int tid = threadIdx.x;
  const int w = tid >> 6;
  const int l = tid & 63;
  const int wr = (w >> 1) * 64;   // wave row offset in tile
  const int wc = (w & 1) * 64;    // wave col offset in tile

  f32x4 acc[4][4];
  #pragma unroll
  for (int mi = 0; mi < 4; ++mi)
    #pragma unroll
    for (int ni = 0; ni < 4; ++ni) acc[mi][ni] = (f32x4){0.f, 0.f, 0.f, 0.f};

  const int lrow = l & 15;          // m (A-frag) / n (B-frag) lane index
  const int qa = (l >> 4) << 3;     // k sub-chunk (elements): 0,8,16,24

  for (int k0 = 0; k0 < K; k0 += 32) {
    __syncthreads();                 // protect LDS from previous iter's readers
    #pragma unroll
    for (int it = 0; it < 2; ++it) {
      const int cb = it * 256 + (w << 6);   // wave-uniform chunk base
      const int c  = cb + l;                // this lane's 16B chunk
      const int r  = c >> 2;                // tile row
      const int qs = ((c & 3) ^ (r & 3)) << 3; // swizzled k-offset (elements)
      gl_lds16(Ab + (long)(row0 + r) * lda + (k0 + qs), &As[cb << 3]);
      gl_lds16(Bb + (long)(col0 + r) * lda + (k0 + qs), &Bs[cb << 3]);
    }
    __syncthreads();

    bf16x8 af[4], bfr[4];
    #pragma unroll
    for (int mi = 0; mi < 4; ++mi) {
      const int R = wr + mi * 16 + lrow;
      af[mi]  = *(const bf16x8*)&As[R * 32 + (qa ^ ((R & 3) << 3))];
    }
    #pragma unroll
    for (int ni = 0; ni < 4; ++ni) {
      const int R = wc + ni * 16 + lrow;
      bfr[ni] = *(const bf16x8*)&Bs[R * 32 + (qa ^ ((R & 3) << 3))];
    }
    #pragma unroll
    for (int mi = 0; mi < 4; ++mi)
      #pragma unroll
      for (int ni = 0; ni < 4; ++ni)
        acc[mi][ni] = __builtin_amdgcn_mfma_f32_16x16x32_bf16(af[mi], bfr[ni], acc[mi][ni], 0, 0, 0);
  }

  // epilogue: C/D frag mapping col=lane&15, row=(lane>>4)*4+reg
  const int rbase = row0 + wr + ((l >> 4) << 2);
  const int cbase = col0 + wc + (l & 15);
  #pragma unroll
  for (int mi = 0; mi < 4; ++mi) {
    #pragma unroll
    for (int ni = 0; ni < 4; ++ni) {
      #pragma unroll
      for (int r = 0; r < 4; ++r) {
        const int i = rbase + mi * 16 + r;
        const int j = cbase + ni * 16;
        const float a = acc[mi][ni][r];
        if constexpr (EPI == 0) {
          Cb[(long)bz * sCz + (long)i * ldc + j] = f2bf(a);
        } else if constexpr (EPI == 1) {
          const float xv = bf2f(Ab[(long)i * K + j]);   // K == D_ here
          Cf[((long)i * B_ + bz) * (long)D_ + j] =
              xv + vec1[bz * D_ + j] * (1.0f / S_) + scale * a;
        } else if constexpr (EPI == 2) {
          const float t = a + vec1[j];
          const float ge = 0.5f * t * (1.0f + erff(t * 0.70710678118654752f));
          Cb[(long)i * ldc + j] = f2bf(ge);
        } else {
          const long idx = (long)i * ldc + j;
          Cf[idx] = Cf[idx] + a + vec1[j];
        }
      }
    }
  }
}

// ---------------------------------------------------------------------------
extern "C" void kernel_launch(void* const* d_in, const int* in_sizes, int n_in,
                              void* d_out, int out_size, void* d_ws, size_t ws_size,
                              hipStream_t stream) {
  (void)in_sizes; (void)n_in; (void)out_size; (void)ws_size;
  const float* x     = (const float*)d_in[0];
  const float* W_v   = (const float*)d_in[1];
  const float* theta = (const float*)d_in[2];
  const float* ln1g  = (const float*)d_in[3];
  const float* ln1b  = (const float*)d_in[4];
  const float* ln2g  = (const float*)d_in[5];
  const float* ln2b  = (const float*)d_in[6];
  const float* w1    = (const float*)d_in[7];
  const float* b1    = (const float*)d_in[8];
  const float* w2    = (const float*)d_in[9];
  const float* b2    = (const float*)d_in[10];
  float* out = (float*)d_out;

  char* ws = (char*)d_ws;
  const size_t MB = 1024ull * 1024ull;
  u16*   Wv_bf = (u16*)(ws + 0);          //  2 MB
  u16*   Th_bf = (u16*)(ws + 2 * MB);     //  2 MB
  u16*   w1_bf = (u16*)(ws + 4 * MB);     //  8 MB
  u16*   w2_bf = (u16*)(ws + 12 * MB);    //  8 MB
  float* first = (float*)(ws + 20 * MB);  // 16 KB
  u16*   Xn    = (u16*)(ws + 24 * MB);    // 32 MB  [B][S][D] bf16 (LN1 out, transposed)
  u16*   XWv   = (u16*)(ws + 56 * MB);    // 32 MB  [B][S][D]
  u16*   Xth   = (u16*)(ws + 88 * MB);    // 32 MB  [B][S][D]
  u16*   Mt    = (u16*)(ws + 120 * MB);   //  8 MB  Mt[b][e][d] = M[b][d][e]
  u16*   h2    = (u16*)(ws + 128 * MB);   // 32 MB  LN2 out bf16 (after Mt done)
  u16*   XthT  = (u16*)(ws + 128 * MB);   // 32 MB  [B][D][S]  (before h2 needed)
  u16*   XWvT  = (u16*)(ws + 160 * MB);   // 32 MB  [B][D][S]
  u16*   G     = (u16*)(ws + 56 * MB);    // 64 MB  gelu chunk [8192][4096] (after Mt done)

  // 1) weights -> bf16
  f2bf_k<<<dim3((D_*D_/4 + 255)/256), 256, 0, stream>>>(W_v,   Wv_bf, D_*D_/4);
  f2bf_k<<<dim3((D_*D_/4 + 255)/256), 256, 0, stream>>>(theta, Th_bf, D_*D_/4);
  f2bf_k<<<dim3((H_*D_/4 + 255)/256), 256, 0, stream>>>(w1,    w1_bf, H_*D_/4);
  f2bf_k<<<dim3((H_*D_/4 + 255)/256), 256, 0, stream>>>(w2,    w2_bf, H_*D_/4);

  // 2) LN1 + transpose to [B][S][D]
  ln_k<true><<<dim3(R_), 256, 0, stream>>>(x, Xn, ln1g, ln1b);

  // 3) XWv = Xn @ W_v^T   (M=16384, N=1024, K=1024)
  gemm_k<0><<<dim3(R_/128, D_/128, 1), 256, 0, stream>>>(
      Xn, 0, Wv_bf, 0, D_, D_, XWv, 0, nullptr, nullptr, 0.f);
  // 4) Xth = Xn @ theta^T
  gemm_k<0><<<dim3(R_/128, D_/128, 1), 256, 0, stream>>>(
      Xn, 0, Th_bf, 0, D_, D_, Xth, 0, nullptr, nullptr, 0.f);

  // 5) first[b][d] = sum_n XWv[b][n][d]
  hipMemsetAsync(first, 0, B_ * D_ * sizeof(float), stream);
  colsum_k<<<dim3(D_/256, 16, B_), 256, 0, stream>>>(XWv, first);

  // 5b) transposes: XWvT[b][e][n], XthT[b][d][n]
  tr_k<<<dim3(D_/64, S_/64, B_), 256, 0, stream>>>(XWv, XWvT);
  tr_k<<<dim3(D_/64, S_/64, B_), 256, 0, stream>>>(Xth, XthT);

  // 6) Mt[b][e][d] = sum_n XWvT[b][e][n] * XthT[b][d][n]   (NT, K=4096)
  gemm_k<0><<<dim3(D_/128, D_/128, B_), 256, 0, stream>>>(
      XWvT, (long)D_*S_, XthT, (long)D_*S_, S_, D_, Mt, (long)D_*D_, nullptr, nullptr, 0.f);

  // 7) h = Xn + first/n + (1/(n*sqrt(D))) * Xn @ Mt^T   -> d_out fp32 [S][B][D]
  gemm_k<1><<<dim3(S_/128, D_/128, B_), 256, 0, stream>>>(
      Xn, (long)S_*D_, Mt, (long)D_*D_, D_, D_, nullptr, 0, out, first,
      1.0f / ((float)S_ * 32.0f));

  // 8) LN2: d_out -> h2 (bf16)
  ln_k<false><<<dim3(R_), 256, 0, stream>>>(out, h2, ln2g, ln2b);

  // 9) MLP in 2 row-chunks of 8192 rows
  for (int c = 0; c < 2; ++c) {
    const long ro = (long)c * 8192;
    // G = gelu(h2 @ w1^T + b1)   (M=8192, N=4096, K=1024)
    gemm_k<2><<<dim3(64, H_/128, 1), 256, 0, stream>>>(
        h2 + ro * D_, 0, w1_bf, 0, D_, H_, G, 0, nullptr, b1, 0.f);
    // out += G @ w2^T + b2       (M=8192, N=1024, K=4096)
    gemm_k<3><<<dim3(64, D_/128, 1), 256, 0, stream>>>(
        G, 0, w2_bf, 0, H_, D_, nullptr, 0, out + ro * D_, b2, 0.f);
  }
}

// Round 3
// 625.184 us; speedup vs baseline: 1.7064x; 1.1728x over previous
//
#include <hip/hip_runtime.h>
#include <math.h>

// Problem dims (fixed by reference)
#define S_ 4096
#define B_ 4
#define D_ 1024
#define R_ (S_*B_)   // 16384 rows
#define H_ (4*D_)    // 4096

typedef unsigned short u16;
typedef unsigned int   u32;
typedef __attribute__((ext_vector_type(8))) short bf16x8;  // 8 bf16 in 4 VGPRs
typedef __attribute__((ext_vector_type(4))) float f32x4;

__device__ __forceinline__ u16 f2bf(float f) {
  u32 u = __float_as_uint(f);
  u32 r = (u + 0x7fffu + ((u >> 16) & 1u)) >> 16;   // RNE
  return (u16)r;
}
__device__ __forceinline__ float bf2f(u16 u) {
  return __uint_as_float(((u32)u) << 16);
}

// async global->LDS, 16B per lane; LDS dest is wave-uniform base + lane*16
__device__ __forceinline__ void gl_lds16(const u16* g, u16* l) {
  __builtin_amdgcn_global_load_lds((const __attribute__((address_space(1))) void*)g,
                                   (__attribute__((address_space(3))) void*)l,
                                   16, 0, 0);
}
// raw barrier with compiler memory fence (no implicit vmcnt drain)
__device__ __forceinline__ void BAR() {
  asm volatile("s_barrier" ::: "memory");
}

// ---------------------------------------------------------------------------
// fp32 -> bf16 convert (vector x4)
__global__ __launch_bounds__(256) void f2bf_k(const float* __restrict__ in,
                                              u16* __restrict__ out, int n4) {
  int i = blockIdx.x * 256 + threadIdx.x;
  if (i < n4) {
    float4 v = ((const float4*)in)[i];
    ushort4 o = make_ushort4(f2bf(v.x), f2bf(v.y), f2bf(v.z), f2bf(v.w));
    ((ushort4*)out)[i] = o;
  }
}

// ---------------------------------------------------------------------------
// LayerNorm over D=1024, one row per 256-thread block, 4 elems/thread.
// TR=true: input row r=(s*B+b) of x[S,B,D] -> output row (b*S+s)
template<bool TR>
__global__ __launch_bounds__(256) void ln_k(const float* __restrict__ x,
                                            u16* __restrict__ o,
                                            const float* __restrict__ g,
                                            const float* __restrict__ bb) {
  const int row = blockIdx.x;
  const int tid = threadIdx.x;
  const float4 v = *(const float4*)&x[(long)row * D_ + tid * 4];
  float vv[4] = {v.x, v.y, v.z, v.w};
  float s = vv[0] + vv[1] + vv[2] + vv[3];
  float q = vv[0]*vv[0] + vv[1]*vv[1] + vv[2]*vv[2] + vv[3]*vv[3];
  const int l = tid & 63, w = tid >> 6;
  #pragma unroll
  for (int off = 32; off > 0; off >>= 1) {
    s += __shfl_down(s, off, 64);
    q += __shfl_down(q, off, 64);
  }
  __shared__ float red[8];
  if (l == 0) { red[w] = s; red[4 + w] = q; }
  __syncthreads();
  s = red[0] + red[1] + red[2] + red[3];
  q = red[4] + red[5] + red[6] + red[7];
  const float m   = s * (1.0f / D_);
  const float var = q * (1.0f / D_) - m * m;
  const float inv = rsqrtf(var + 1e-5f);
  const long orow = TR ? ((long)(row % B_) * S_ + (row / B_)) : (long)row;
  const int j = tid * 4;
  ushort4 ou = make_ushort4(
      f2bf((vv[0] - m) * inv * g[j+0] + bb[j+0]),
      f2bf((vv[1] - m) * inv * g[j+1] + bb[j+1]),
      f2bf((vv[2] - m) * inv * g[j+2] + bb[j+2]),
      f2bf((vv[3] - m) * inv * g[j+3] + bb[j+3]));
  *(ushort4*)&o[orow * D_ + j] = ou;
}

// ---------------------------------------------------------------------------
// column sums of XWv: first[b][d] = sum_n XWv[b][n][d]
__global__ __launch_bounds__(256) void colsum_k(const u16* __restrict__ Xw,
                                                float* __restrict__ first) {
  const int d  = blockIdx.x * 256 + threadIdx.x;
  const int b  = blockIdx.z;
  const int n0 = blockIdx.y * 256;
  const u16* p = Xw + ((long)b * S_ + n0) * D_ + d;
  float s = 0.f;
  #pragma unroll 8
  for (int n = 0; n < 256; ++n) s += bf2f(p[(long)n * D_]);
  atomicAdd(&first[b * D_ + d], s);
}

// ---------------------------------------------------------------------------
// 64x64 bf16 transpose: in [b][S_][D_] -> out [b][D_][S_]
__global__ __launch_bounds__(256) void tr_k(const u16* __restrict__ in,
                                            u16* __restrict__ out) {
  __shared__ u16 t[64][65];
  const int b  = blockIdx.z;
  const int e0 = blockIdx.x * 64;
  const int n0 = blockIdx.y * 64;
  const int tid = threadIdx.x;
  #pragma unroll
  for (int i = 0; i < 4; ++i) {
    const int v = i * 256 + tid;
    const int r = v >> 4;            // n-offset 0..63
    const int c = (v & 15) << 2;     // e-offset
    ushort4 d4 = *(const ushort4*)&in[((long)b * S_ + n0 + r) * D_ + e0 + c];
    t[r][c+0] = d4.x; t[r][c+1] = d4.y; t[r][c+2] = d4.z; t[r][c+3] = d4.w;
  }
  __syncthreads();
  #pragma unroll
  for (int i = 0; i < 4; ++i) {
    const int v = i * 256 + tid;
    const int e = v >> 4;
    const int c = (v & 15) << 2;
    ushort4 o4 = make_ushort4(t[c+0][e], t[c+1][e], t[c+2][e], t[c+3][e]);
    *(ushort4*)&out[((long)b * D_ + e0 + e) * S_ + n0 + c] = o4;
  }
}

// ---------------------------------------------------------------------------
// 128x128-tile NT GEMM (kept for Mt: per-batch 1024x1024, K=4096).
// Swizzle: LDS chunk (r,q) holds global chunk (r, q ^ ((r>>1)&3)) -> 8-bank spread.
template<int EPI>
__global__ __launch_bounds__(256, 2) void gemm_k(
    const u16* __restrict__ A, long sAz,
    const u16* __restrict__ B, long sBz,
    int K, int ldc,
    u16* __restrict__ Cb, long sCz,
    float* __restrict__ Cf,
    const float* __restrict__ vec1,
    float scale)
{
  const int bz = blockIdx.z;
  const u16* Ab = A + (long)bz * sAz;
  const u16* Bb = B + (long)bz * sBz;
  const int row0 = blockIdx.x * 128;
  const int col0 = blockIdx.y * 128;
  const int lda = K;

  __shared__ __align__(16) u16 As[128 * 32];
  __shared__ __align__(16) u16 Bs[128 * 32];

  const int tid = threadIdx.x;
  const int w = tid >> 6;
  const int l = tid & 63;
  const int wr = (w >> 1) * 64;
  const int wc = (w & 1) * 64;

  f32x4 acc[4][4];
  #pragma unroll
  for (int mi = 0; mi < 4; ++mi)
    #pragma unroll
    for (int ni = 0; ni < 4; ++ni) acc[mi][ni] = (f32x4){0.f, 0.f, 0.f, 0.f};

  const int lrow = l & 15;
  const int lo   = l >> 4;

  for (int k0 = 0; k0 < K; k0 += 32) {
    __syncthreads();
    #pragma unroll
    for (int it = 0; it < 2; ++it) {
      const int cb = it * 256 + (w << 6);
      const int c  = cb + l;
      const int r  = c >> 2;
      const int qs = ((c & 3) ^ ((r >> 1) & 3)) << 3;
      gl_lds16(Ab + (long)(row0 + r) * lda + (k0 + qs), &As[cb << 3]);
      gl_lds16(Bb + (long)(col0 + r) * lda + (k0 + qs), &Bs[cb << 3]);
    }
    __syncthreads();

    bf16x8 af[4], bfr[4];
    #pragma unroll
    for (int mi = 0; mi < 4; ++mi) {
      const int R = wr + mi * 16 + lrow;
      af[mi]  = *(const bf16x8*)&As[R * 32 + ((lo ^ ((R >> 1) & 3)) << 3)];
    }
    #pragma unroll
    for (int ni = 0; ni < 4; ++ni) {
      const int R = wc + ni * 16 + lrow;
      bfr[ni] = *(const bf16x8*)&Bs[R * 32 + ((lo ^ ((R >> 1) & 3)) << 3)];
    }
    #pragma unroll
    for (int mi = 0; mi < 4; ++mi)
      #pragma unroll
      for (int ni = 0; ni < 4; ++ni)
        acc[mi][ni] = __builtin_amdgcn_mfma_f32_16x16x32_bf16(af[mi], bfr[ni], acc[mi][ni], 0, 0, 0);
  }

  const int rbase = row0 + wr + (lo << 2);
  const int cbase = col0 + wc + lrow;
  #pragma unroll
  for (int mi = 0; mi < 4; ++mi)
    #pragma unroll
    for (int ni = 0; ni < 4; ++ni)
      #pragma unroll
      for (int r = 0; r < 4; ++r) {
        const int i = rbase + mi * 16 + r;
        const int j = cbase + ni * 16;
        if constexpr (EPI == 0)
          Cb[(long)bz * sCz + (long)i * ldc + j] = f2bf(acc[mi][ni][r]);
      }
  (void)Cf; (void)vec1; (void)scale;
}

// ---------------------------------------------------------------------------
// 256x256-tile NT GEMM, BK=64, 512 threads = 8 waves (2M x 4N), 4-phase
// pipelined schedule: double-buffered 128 KB LDS, full next-tile prefetch
// issued at phase 0, vmcnt(0) drain only at tile boundary (covered by ~4
// phases of MFMA), setprio around MFMA clusters, conflict-free chunk swizzle
// (LDS chunk (r,q) <-> global chunk (r, q^(r&7)), involution).
// C[i,j] = sum_k A[i*K+k]*B[j*K+k].
template<int EPI>
__global__ __launch_bounds__(512, 2) void gemm256_k(
    const u16* __restrict__ A, long sAz,
    const u16* __restrict__ B, long sBz,
    int K, int ldc,
    u16* __restrict__ Cb, long sCz,
    float* __restrict__ Cf,
    const float* __restrict__ vec1,
    float scale)
{
  const int bz = blockIdx.z;
  const u16* Ab = A + (long)bz * sAz;
  const u16* Bb = B + (long)bz * sBz;
  const int row0 = blockIdx.x * 256;
  const int col0 = blockIdx.y * 256;

  __shared__ __align__(16) u16 As[2][256 * 64];
  __shared__ __align__(16) u16 Bs[2][256 * 64];

  const int tid = threadIdx.x;
  const int w   = tid >> 6;       // wave 0..7
  const int l   = tid & 63;
  const int wm  = w >> 2;         // 0..1  (row half)
  const int wn  = w & 3;          // 0..3  (col quarter)
  const int lr  = l & 15;
  const int lo  = l >> 4;         // 0..3

  // staging geometry: wave w instr i covers LDS chunks [(w*4+i)*64 + l]
  // -> r = w*32 + i*8 + (l>>3), q = l&7 ; source chunk = q ^ (r&7) = (l&7)^(l>>3)
  const int rstage = w * 32 + (l >> 3);
  const int qst    = ((l & 7) ^ (l >> 3)) << 3;   // element offset in row

  // frag-read swizzled chunk offsets (elements): q_l = (kh*4+lo) ^ (lr&7)
  const int qa0 = ((0 + lo) ^ (lr & 7)) << 3;
  const int qa1 = ((4 + lo) ^ (lr & 7)) << 3;

  f32x4 acc[8][4];
  #pragma unroll
  for (int mi = 0; mi < 8; ++mi)
    #pragma unroll
    for (int ni = 0; ni < 4; ++ni) acc[mi][ni] = (f32x4){0.f, 0.f, 0.f, 0.f};

  const int NT = K >> 6;

  auto STAGE = [&](int tn, int buf) {
    const long ko = (long)tn * 64;
    const u16* asrc = Ab + (long)(row0 + rstage) * K + ko + qst;
    const u16* bsrc = Bb + (long)(col0 + rstage) * K + ko + qst;
    u16* ald = &As[buf][(w * 4) * 512];
    u16* bld = &Bs[buf][(w * 4) * 512];
    #pragma unroll
    for (int i = 0; i < 4; ++i) {
      gl_lds16(asrc + (long)(i * 8) * K, ald + i * 512);
      gl_lds16(bsrc + (long)(i * 8) * K, bld + i * 512);
    }
  };

  // prologue: stage tile 0, full drain
  STAGE(0, 0);
  __syncthreads();

  for (int t = 0; t < NT; ++t) {
    const int cur = t & 1;
    const u16* Ac = As[cur];
    const u16* Bc = Bs[cur];
    bf16x8 af[4], bf[4];

    // ---- phase 0: kh=0, rows wm*128+[0,64) ----
    #pragma unroll
    for (int ni = 0; ni < 4; ++ni)
      bf[ni] = *(const bf16x8*)&Bc[(wn * 64 + ni * 16 + lr) * 64 + qa0];
    #pragma unroll
    for (int mi = 0; mi < 4; ++mi)
      af[mi] = *(const bf16x8*)&Ac[(wm * 128 + mi * 16 + lr) * 64 + qa0];
    if (t + 1 < NT) STAGE(t + 1, cur ^ 1);
    BAR();
    __builtin_amdgcn_s_setprio(1);
    #pragma unroll
    for (int mi = 0; mi < 4; ++mi)
      #pragma unroll
      for (int ni = 0; ni < 4; ++ni)
        acc[mi][ni] = __builtin_amdgcn_mfma_f32_16x16x32_bf16(af[mi], bf[ni], acc[mi][ni], 0, 0, 0);
    __builtin_amdgcn_s_setprio(0);
    BAR();

    // ---- phase 1: kh=0, rows wm*128+[64,128) ----
    #pragma unroll
    for (int mi = 0; mi < 4; ++mi)
      af[mi] = *(const bf16x8*)&Ac[(wm * 128 + 64 + mi * 16 + lr) * 64 + qa0];
    BAR();
    __builtin_amdgcn_s_setprio(1);
    #pragma unroll
    for (int mi = 0; mi < 4; ++mi)
      #pragma unroll
      for (int ni = 0; ni < 4; ++ni)
        acc[4 + mi][ni] = __builtin_amdgcn_mfma_f32_16x16x32_bf16(af[mi], bf[ni], acc[4 + mi][ni], 0, 0, 0);
    __builtin_amdgcn_s_setprio(0);
    BAR();

    // ---- phase 2: kh=1, rows wm*128+[0,64) ----
    #pragma unroll
    for (int ni = 0; ni < 4; ++ni)
      bf[ni] = *(const bf16x8*)&Bc[(wn * 64 + ni * 16 + lr) * 64 + qa1];
    #pragma unroll
    for (int mi = 0; mi < 4; ++mi)
      af[mi] = *(const bf16x8*)&Ac[(wm * 128 + mi * 16 + lr) * 64 + qa1];
    BAR();
    __builtin_amdgcn_s_setprio(1);
    #pragma unroll
    for (int mi = 0; mi < 4; ++mi)
      #pragma unroll
      for (int ni = 0; ni < 4; ++ni)
        acc[mi][ni] = __builtin_amdgcn_mfma_f32_16x16x32_bf16(af[mi], bf[ni], acc[mi][ni], 0, 0, 0);
    __builtin_amdgcn_s_setprio(0);
    BAR();

    // ---- phase 3: kh=1, rows wm*128+[64,128) ----
    #pragma unroll
    for (int mi = 0; mi < 4; ++mi)
      af[mi] = *(const bf16x8*)&Ac[(wm * 128 + 64 + mi * 16 + lr) * 64 + qa1];
    BAR();
    __builtin_amdgcn_s_setprio(1);
    #pragma unroll
    for (int mi = 0; mi < 4; ++mi)
      #pragma unroll
      for (int ni = 0; ni < 4; ++ni)
        acc[4 + mi][ni] = __builtin_amdgcn_mfma_f32_16x16x32_bf16(af[mi], bf[ni], acc[4 + mi][ni], 0, 0, 0);
    __builtin_amdgcn_s_setprio(0);
    // tile boundary: next tile's LDS must be complete & visible
    asm volatile("s_waitcnt vmcnt(0)" ::: "memory");
    BAR();
  }

  // epilogue: C/D frag mapping col=lane&15, row=(lane>>4)*4+reg
  const int rbase = row0 + wm * 128 + (lo << 2);
  const int cbase = col0 + wn * 64 + lr;
  #pragma unroll
  for (int mi = 0; mi < 8; ++mi) {
    #pragma unroll
    for (int ni = 0; ni < 4; ++ni) {
      #pragma unroll
      for (int r = 0; r < 4; ++r) {
        const int i = rbase + mi * 16 + r;
        const int j = cbase + ni * 16;
        const float a = acc[mi][ni][r];
        if constexpr (EPI == 0) {
          Cb[(long)bz * sCz + (long)i * ldc + j] = f2bf(a);
        } else if constexpr (EPI == 1) {
          const float xv = bf2f(Ab[(long)i * K + j]);   // K == D_ here
          Cf[((long)i * B_ + bz) * (long)D_ + j] =
              xv + vec1[bz * D_ + j] * (1.0f / S_) + scale * a;
        } else if constexpr (EPI == 2) {
          const float tt = a + vec1[j];
          const float ge = 0.5f * tt * (1.0f + erff(tt * 0.70710678118654752f));
          Cb[(long)i * ldc + j] = f2bf(ge);
        } else {
          const long idx = (long)i * ldc + j;
          Cf[idx] = Cf[idx] + a + vec1[j];
        }
      }
    }
  }
}

// ---------------------------------------------------------------------------
extern "C" void kernel_launch(void* const* d_in, const int* in_sizes, int n_in,
                              void* d_out, int out_size, void* d_ws, size_t ws_size,
                              hipStream_t stream) {
  (void)in_sizes; (void)n_in; (void)out_size; (void)ws_size;
  const float* x     = (const float*)d_in[0];
  const float* W_v   = (const float*)d_in[1];
  const float* theta = (const float*)d_in[2];
  const float* ln1g  = (const float*)d_in[3];
  const float* ln1b  = (const float*)d_in[4];
  const float* ln2g  = (const float*)d_in[5];
  const float* ln2b  = (const float*)d_in[6];
  const float* w1    = (const float*)d_in[7];
  const float* b1    = (const float*)d_in[8];
  const float* w2    = (const float*)d_in[9];
  const float* b2    = (const float*)d_in[10];
  float* out = (float*)d_out;

  char* ws = (char*)d_ws;
  const size_t MB = 1024ull * 1024ull;
  const size_t KB = 1024ull;
  u16*   Wv_bf = (u16*)(ws + 0);              //  2 MB   (Th must follow contiguously)
  u16*   Th_bf = (u16*)(ws + 2 * MB);         //  2 MB
  u16*   w1_bf = (u16*)(ws + 4 * MB);         //  8 MB
  u16*   w2_bf = (u16*)(ws + 12 * MB);        //  8 MB
  float* first = (float*)(ws + 20 * MB);      // 16 KB
  u16*   Mt    = (u16*)(ws + 21 * MB);        //  8 MB  Mt[b][e][d] = M[b][d][e]
  u16*   Xn    = (u16*)(ws + 29 * MB);        // 32 MB  [B][S][D] (LN1 out, transposed)
  u16*   XWv   = (u16*)(ws + 61 * MB);        // 32 MB  (XWv,Xth contiguous: z-stride)
  u16*   Xth   = (u16*)(ws + 93 * MB);        // 32 MB
  u16*   XWvT  = (u16*)(ws + 125 * MB);       // 32 MB  [B][D][S]
  u16*   XthT  = (u16*)(ws + 157 * MB);       // 32 MB  (ends 189 MB)
  u16*   h2    = (u16*)(ws + 29 * MB);        // 32 MB  (over dead Xn)
  u16*   G     = (u16*)(ws + 61 * MB);        // 128 MB [16384][4096] (over dead XWv..XthT)
  (void)KB;

  // 1) weights -> bf16
  f2bf_k<<<dim3((D_*D_/4 + 255)/256), 256, 0, stream>>>(W_v,   Wv_bf, D_*D_/4);
  f2bf_k<<<dim3((D_*D_/4 + 255)/256), 256, 0, stream>>>(theta, Th_bf, D_*D_/4);
  f2bf_k<<<dim3((H_*D_/4 + 255)/256), 256, 0, stream>>>(w1,    w1_bf, H_*D_/4);
  f2bf_k<<<dim3((H_*D_/4 + 255)/256), 256, 0, stream>>>(w2,    w2_bf, H_*D_/4);

  // 2) LN1 + transpose to [B][S][D]
  ln_k<true><<<dim3(R_), 256, 0, stream>>>(x, Xn, ln1g, ln1b);

  // 3+4) XWv / Xth in one dispatch (z picks weight & dest; A shared = Xn)
  gemm256_k<0><<<dim3(R_/256, D_/256, 2), 512, 0, stream>>>(
      Xn, 0, Wv_bf, (long)D_*D_, D_, D_, XWv, (long)R_*D_, nullptr, nullptr, 0.f);

  // 5) first[b][d] = sum_n XWv[b][n][d]
  hipMemsetAsync(first, 0, B_ * D_ * sizeof(float), stream);
  colsum_k<<<dim3(D_/256, 16, B_), 256, 0, stream>>>(XWv, first);

  // 5b) transposes
  tr_k<<<dim3(D_/64, S_/64, B_), 256, 0, stream>>>(XWv, XWvT);
  tr_k<<<dim3(D_/64, S_/64, B_), 256, 0, stream>>>(Xth, XthT);

  // 6) Mt[b][e][d] = sum_n XWvT[b][e][n] * XthT[b][d][n]   (128-tile, K=4096)
  gemm_k<0><<<dim3(D_/128, D_/128, B_), 256, 0, stream>>>(
      XWvT, (long)D_*S_, XthT, (long)D_*S_, S_, D_, Mt, (long)D_*D_, nullptr, nullptr, 0.f);

  // 7) h = Xn + first/n + (1/(n*sqrt(D))) * Xn @ Mt^T -> d_out fp32 [S][B][D]
  gemm256_k<1><<<dim3(S_/256, D_/256, B_), 512, 0, stream>>>(
      Xn, (long)S_*D_, Mt, (long)D_*D_, D_, D_, nullptr, 0, out, first,
      1.0f / ((float)S_ * 32.0f));

  // 8) LN2: d_out -> h2 (bf16)
  ln_k<false><<<dim3(R_), 256, 0, stream>>>(out, h2, ln2g, ln2b);

  // 9) MLP, full M=16384
  gemm256_k<2><<<dim3(R_/256, H_/256, 1), 512, 0, stream>>>(
      h2, 0, w1_bf, 0, D_, H_, G, 0, nullptr, b1, 0.f);
  gemm256_k<3><<<dim3(R_/256, D_/256, 1), 512, 0, stream>>>(
      G, 0, w2_bf, 0, H_, D_, nullptr, 0, out, b2, 0.f);
}

// Round 4
// 607.099 us; speedup vs baseline: 1.7572x; 1.0298x over previous
//
#include <hip/hip_runtime.h>
#include <math.h>

// Problem dims (fixed by reference)
#define S_ 4096
#define B_ 4
#define D_ 1024
#define R_ (S_*B_)   // 16384 rows
#define H_ (4*D_)    // 4096

typedef unsigned short u16;
typedef unsigned int   u32;
typedef __attribute__((ext_vector_type(8))) short bf16x8;  // 8 bf16 in 4 VGPRs
typedef __attribute__((ext_vector_type(4))) float f32x4;

__device__ __forceinline__ u16 f2bf(float f) {
  u32 u = __float_as_uint(f);
  u32 r = (u + 0x7fffu + ((u >> 16) & 1u)) >> 16;   // RNE
  return (u16)r;
}
__device__ __forceinline__ float bf2f(u16 u) {
  return __uint_as_float(((u32)u) << 16);
}

// async global->LDS, 16B per lane; LDS dest is wave-uniform base + lane*16
__device__ __forceinline__ void gl_lds16(const u16* g, u16* l) {
  __builtin_amdgcn_global_load_lds((const __attribute__((address_space(1))) void*)g,
                                   (__attribute__((address_space(3))) void*)l,
                                   16, 0, 0);
}
// raw barrier with compiler memory fence (no implicit vmcnt drain)
__device__ __forceinline__ void BAR() {
  asm volatile("s_barrier" ::: "memory");
}

// fast GELU (tanh form): max |err| ~1e-3, far below bf16 quantum here.
__device__ __forceinline__ float gelu_f(float t) {
  const float u2 = 1.5957691216f * t + 0.0713548162726f * t * t * t; // 2*0.7978845608*(t+0.044715t^3)
  return t / (1.0f + __expf(-u2));
}

// ---------------------------------------------------------------------------
// fp32 -> bf16 convert (vector x4)
__global__ __launch_bounds__(256) void f2bf_k(const float* __restrict__ in,
                                              u16* __restrict__ out, int n4) {
  int i = blockIdx.x * 256 + threadIdx.x;
  if (i < n4) {
    float4 v = ((const float4*)in)[i];
    ushort4 o = make_ushort4(f2bf(v.x), f2bf(v.y), f2bf(v.z), f2bf(v.w));
    ((ushort4*)out)[i] = o;
  }
}

// ---------------------------------------------------------------------------
// LayerNorm over D=1024, one row per 256-thread block, 4 elems/thread.
// TR=true: input row r=(s*B+b) of x[S,B,D] -> output row (b*S+s)
template<bool TR>
__global__ __launch_bounds__(256) void ln_k(const float* __restrict__ x,
                                            u16* __restrict__ o,
                                            const float* __restrict__ g,
                                            const float* __restrict__ bb) {
  const int row = blockIdx.x;
  const int tid = threadIdx.x;
  const float4 v = *(const float4*)&x[(long)row * D_ + tid * 4];
  float vv[4] = {v.x, v.y, v.z, v.w};
  float s = vv[0] + vv[1] + vv[2] + vv[3];
  float q = vv[0]*vv[0] + vv[1]*vv[1] + vv[2]*vv[2] + vv[3]*vv[3];
  const int l = tid & 63, w = tid >> 6;
  #pragma unroll
  for (int off = 32; off > 0; off >>= 1) {
    s += __shfl_down(s, off, 64);
    q += __shfl_down(q, off, 64);
  }
  __shared__ float red[8];
  if (l == 0) { red[w] = s; red[4 + w] = q; }
  __syncthreads();
  s = red[0] + red[1] + red[2] + red[3];
  q = red[4] + red[5] + red[6] + red[7];
  const float m   = s * (1.0f / D_);
  const float var = q * (1.0f / D_) - m * m;
  const float inv = rsqrtf(var + 1e-5f);
  const long orow = TR ? ((long)(row % B_) * S_ + (row / B_)) : (long)row;
  const int j = tid * 4;
  ushort4 ou = make_ushort4(
      f2bf((vv[0] - m) * inv * g[j+0] + bb[j+0]),
      f2bf((vv[1] - m) * inv * g[j+1] + bb[j+1]),
      f2bf((vv[2] - m) * inv * g[j+2] + bb[j+2]),
      f2bf((vv[3] - m) * inv * g[j+3] + bb[j+3]));
  *(ushort4*)&o[orow * D_ + j] = ou;
}

// ---------------------------------------------------------------------------
// column sums of XWv: first[b][d] = sum_n XWv[b][n][d]
__global__ __launch_bounds__(256) void colsum_k(const u16* __restrict__ Xw,
                                                float* __restrict__ first) {
  const int d  = blockIdx.x * 256 + threadIdx.x;
  const int b  = blockIdx.z;
  const int n0 = blockIdx.y * 256;
  const u16* p = Xw + ((long)b * S_ + n0) * D_ + d;
  float s = 0.f;
  #pragma unroll 8
  for (int n = 0; n < 256; ++n) s += bf2f(p[(long)n * D_]);
  atomicAdd(&first[b * D_ + d], s);
}

// ---------------------------------------------------------------------------
// 64x64 bf16 transpose: in [b][S_][D_] -> out [b][D_][S_]
__global__ __launch_bounds__(256) void tr_k(const u16* __restrict__ in,
                                            u16* __restrict__ out) {
  __shared__ u16 t[64][65];
  const int b  = blockIdx.z;
  const int e0 = blockIdx.x * 64;
  const int n0 = blockIdx.y * 64;
  const int tid = threadIdx.x;
  #pragma unroll
  for (int i = 0; i < 4; ++i) {
    const int v = i * 256 + tid;
    const int r = v >> 4;            // n-offset 0..63
    const int c = (v & 15) << 2;     // e-offset
    ushort4 d4 = *(const ushort4*)&in[((long)b * S_ + n0 + r) * D_ + e0 + c];
    t[r][c+0] = d4.x; t[r][c+1] = d4.y; t[r][c+2] = d4.z; t[r][c+3] = d4.w;
  }
  __syncthreads();
  #pragma unroll
  for (int i = 0; i < 4; ++i) {
    const int v = i * 256 + tid;
    const int e = v >> 4;
    const int c = (v & 15) << 2;
    ushort4 o4 = make_ushort4(t[c+0][e], t[c+1][e], t[c+2][e], t[c+3][e]);
    *(ushort4*)&out[((long)b * D_ + e0 + e) * S_ + n0 + c] = o4;
  }
}

// ---------------------------------------------------------------------------
// 128x128-tile NT GEMM (kept for Mt: per-batch 1024x1024, K=4096).
template<int EPI>
__global__ __launch_bounds__(256, 2) void gemm_k(
    const u16* __restrict__ A, long sAz,
    const u16* __restrict__ B, long sBz,
    int K, int ldc,
    u16* __restrict__ Cb, long sCz,
    float* __restrict__ Cf,
    const float* __restrict__ vec1,
    float scale)
{
  const int bz = blockIdx.z;
  const u16* Ab = A + (long)bz * sAz;
  const u16* Bb = B + (long)bz * sBz;
  const int row0 = blockIdx.x * 128;
  const int col0 = blockIdx.y * 128;
  const int lda = K;

  __shared__ __align__(16) u16 As[128 * 32];
  __shared__ __align__(16) u16 Bs[128 * 32];

  const int tid = threadIdx.x;
  const int w = tid >> 6;
  const int l = tid & 63;
  const int wr = (w >> 1) * 64;
  const int wc = (w & 1) * 64;

  f32x4 acc[4][4];
  #pragma unroll
  for (int mi = 0; mi < 4; ++mi)
    #pragma unroll
    for (int ni = 0; ni < 4; ++ni) acc[mi][ni] = (f32x4){0.f, 0.f, 0.f, 0.f};

  const int lrow = l & 15;
  const int lo   = l >> 4;

  for (int k0 = 0; k0 < K; k0 += 32) {
    __syncthreads();
    #pragma unroll
    for (int it = 0; it < 2; ++it) {
      const int cb = it * 256 + (w << 6);
      const int c  = cb + l;
      const int r  = c >> 2;
      const int qs = ((c & 3) ^ ((r >> 1) & 3)) << 3;
      gl_lds16(Ab + (long)(row0 + r) * lda + (k0 + qs), &As[cb << 3]);
      gl_lds16(Bb + (long)(col0 + r) * lda + (k0 + qs), &Bs[cb << 3]);
    }
    __syncthreads();

    bf16x8 af[4], bfr[4];
    #pragma unroll
    for (int mi = 0; mi < 4; ++mi) {
      const int R = wr + mi * 16 + lrow;
      af[mi]  = *(const bf16x8*)&As[R * 32 + ((lo ^ ((R >> 1) & 3)) << 3)];
    }
    #pragma unroll
    for (int ni = 0; ni < 4; ++ni) {
      const int R = wc + ni * 16 + lrow;
      bfr[ni] = *(const bf16x8*)&Bs[R * 32 + ((lo ^ ((R >> 1) & 3)) << 3)];
    }
    #pragma unroll
    for (int mi = 0; mi < 4; ++mi)
      #pragma unroll
      for (int ni = 0; ni < 4; ++ni)
        acc[mi][ni] = __builtin_amdgcn_mfma_f32_16x16x32_bf16(af[mi], bfr[ni], acc[mi][ni], 0, 0, 0);
  }

  const int rbase = row0 + wr + (lo << 2);
  const int cbase = col0 + wc + lrow;
  #pragma unroll
  for (int mi = 0; mi < 4; ++mi)
    #pragma unroll
    for (int ni = 0; ni < 4; ++ni)
      #pragma unroll
      for (int r = 0; r < 4; ++r) {
        const int i = rbase + mi * 16 + r;
        const int j = cbase + ni * 16;
        if constexpr (EPI == 0)
          Cb[(long)bz * sCz + (long)i * ldc + j] = f2bf(acc[mi][ni][r]);
      }
  (void)Cf; (void)vec1; (void)scale;
}

// ---------------------------------------------------------------------------
// 256x256-tile NT GEMM, BK=64, 512 threads = 8 waves (2M x 4N).
// Deep-pipelined m201-style schedule:
//  - staging unit = one operand K-half [256 rows][32 cols] = 16 KB, 2 loads/thread
//  - ring L[db][kh][op] of 8 units (128 KB LDS)
//  - per phase: ds_reads -> stage ONE unit (6 phases ahead of use) -> [vmcnt] ->
//    barrier -> setprio(1) 16 MFMA setprio(0) -> barrier
//  - counted vmcnt(8) (wait-for-oldest; 4 units = 8 loads stay in flight)
//  - chunk swizzle q ^ ((R>>1)&3): stage source pre-swizzled, reads apply same XOR
// C[i,j] = sum_k A[i*K+k]*B[j*K+k].
template<int EPI>
__global__ __launch_bounds__(512, 2) void gemm256_k(
    const u16* __restrict__ A, long sAz,
    const u16* __restrict__ B, long sBz,
    int K, int ldc,
    u16* __restrict__ Cb, long sCz,
    float* __restrict__ Cf,
    const float* __restrict__ vec1,
    float scale)
{
  const int bz = blockIdx.z;
  const u16* Ab = A + (long)bz * sAz;
  const u16* Bb = B + (long)bz * sBz;
  const int row0 = blockIdx.x * 256;
  const int col0 = blockIdx.y * 256;

  // [dbuf][khalf][op][256*32]
  __shared__ __align__(16) u16 Lds[2][2][2][256 * 32];

  const int tid = threadIdx.x;
  const int w   = tid >> 6;       // wave 0..7
  const int l   = tid & 63;
  const int wm  = w >> 2;         // 0..1  (row half)
  const int wn  = w & 3;          // 0..3  (col quarter)
  const int lr  = l & 15;
  const int lo  = l >> 4;         // 0..3

  const int NKH = K >> 5;         // number of K-halves
  const int NT  = K >> 6;         // number of K-tiles

  // stage geometry (per load i in {0,1}): R = w*32 + i*16 + (l>>2), src chunk = (l&3)^((l>>3)&3)
  const int rs   = w * 32 + (l >> 2);
  const int qsrc = ((l & 3) ^ ((l >> 3) & 3)) << 3;   // element offset

  // read-side swizzled chunk (elements): (lo ^ ((lr>>1)&3)) * 8
  const int qsw = (lo ^ ((lr >> 1) & 3)) << 3;

  // stage one operand K-half unit
  auto STAGE = [&](int khg, int op) {
    if (khg >= NKH) return;
    const u16* src = (op ? Bb : Ab) + (long)((op ? col0 : row0) + rs) * K + khg * 32 + qsrc;
    u16* dst = &Lds[(khg >> 1) & 1][khg & 1][op][(w * 2) * 512];
    gl_lds16(src, dst);
    gl_lds16(src + (long)16 * K, dst + 512);
  };

  f32x4 acc[8][4];
  #pragma unroll
  for (int mi = 0; mi < 8; ++mi)
    #pragma unroll
    for (int ni = 0; ni < 4; ++ni) acc[mi][ni] = (f32x4){0.f, 0.f, 0.f, 0.f};

  // prologue: stage K-halves 0..2 (A,B each) = 12 loads/thread
  STAGE(0, 0); STAGE(0, 1);
  STAGE(1, 0); STAGE(1, 1);
  STAGE(2, 0); STAGE(2, 1);
  asm volatile("s_waitcnt vmcnt(8)" ::: "memory");   // A,B(0) landed
  BAR();

  for (int kt = 0; kt < NT; ++kt) {
    const u16* L00 = &Lds[kt & 1][0][0][0];  // A, kh=0
    const u16* L01 = &Lds[kt & 1][0][1][0];  // B, kh=0
    const u16* L10 = &Lds[kt & 1][1][0][0];  // A, kh=1
    const u16* L11 = &Lds[kt & 1][1][1][0];  // B, kh=1
    bf16x8 af[4], bf[4];

    // ---- phase 0: kh=0, mh=0 ----
    #pragma unroll
    for (int ni = 0; ni < 4; ++ni)
      bf[ni] = *(const bf16x8*)&L01[(wn * 64 + ni * 16 + lr) * 32 + qsw];
    #pragma unroll
    for (int mi = 0; mi < 4; ++mi)
      af[mi] = *(const bf16x8*)&L00[(wm * 128 + mi * 16 + lr) * 32 + qsw];
    STAGE(2 * kt + 3, 0);
    BAR();
    __builtin_amdgcn_s_setprio(1);
    #pragma unroll
    for (int mi = 0; mi < 4; ++mi)
      #pragma unroll
      for (int ni = 0; ni < 4; ++ni)
        acc[mi][ni] = __builtin_amdgcn_mfma_f32_16x16x32_bf16(af[mi], bf[ni], acc[mi][ni], 0, 0, 0);
    __builtin_amdgcn_s_setprio(0);
    BAR();

    // ---- phase 1: kh=0, mh=1 ----
    #pragma unroll
    for (int mi = 0; mi < 4; ++mi)
      af[mi] = *(const bf16x8*)&L00[(wm * 128 + 64 + mi * 16 + lr) * 32 + qsw];
    STAGE(2 * kt + 3, 1);
    if (kt == NT - 1) asm volatile("s_waitcnt vmcnt(0)" ::: "memory");
    else              asm volatile("s_waitcnt vmcnt(8)" ::: "memory");
    BAR();
    __builtin_amdgcn_s_setprio(1);
    #pragma unroll
    for (int mi = 0; mi < 4; ++mi)
      #pragma unroll
      for (int ni = 0; ni < 4; ++ni)
        acc[4 + mi][ni] = __builtin_amdgcn_mfma_f32_16x16x32_bf16(af[mi], bf[ni], acc[4 + mi][ni], 0, 0, 0);
    __builtin_amdgcn_s_setprio(0);
    BAR();

    // ---- phase 2: kh=1, mh=0 ----
    #pragma unroll
    for (int ni = 0; ni < 4; ++ni)
      bf[ni] = *(const bf16x8*)&L11[(wn * 64 + ni * 16 + lr) * 32 + qsw];
    #pragma unroll
    for (int mi = 0; mi < 4; ++mi)
      af[mi] = *(const bf16x8*)&L10[(wm * 128 + mi * 16 + lr) * 32 + qsw];
    STAGE(2 * kt + 4, 0);
    BAR();
    __builtin_amdgcn_s_setprio(1);
    #pragma unroll
    for (int mi = 0; mi < 4; ++mi)
      #pragma unroll
      for (int ni = 0; ni < 4; ++ni)
        acc[mi][ni] = __builtin_amdgcn_mfma_f32_16x16x32_bf16(af[mi], bf[ni], acc[mi][ni], 0, 0, 0);
    __builtin_amdgcn_s_setprio(0);
    BAR();

    // ---- phase 3: kh=1, mh=1 ----
    #pragma unroll
    for (int mi = 0; mi < 4; ++mi)
      af[mi] = *(const bf16x8*)&L10[(wm * 128 + 64 + mi * 16 + lr) * 32 + qsw];
    STAGE(2 * kt + 4, 1);
    if (kt < NT - 2)       asm volatile("s_waitcnt vmcnt(8)" ::: "memory");
    else if (kt == NT - 2) asm volatile("s_waitcnt vmcnt(4)" ::: "memory");
    else                   asm volatile("s_waitcnt vmcnt(0)" ::: "memory");
    BAR();
    __builtin_amdgcn_s_setprio(1);
    #pragma unroll
    for (int mi = 0; mi < 4; ++mi)
      #pragma unroll
      for (int ni = 0; ni < 4; ++ni)
        acc[4 + mi][ni] = __builtin_amdgcn_mfma_f32_16x16x32_bf16(af[mi], bf[ni], acc[4 + mi][ni], 0, 0, 0);
    __builtin_amdgcn_s_setprio(0);
    BAR();
  }

  // epilogue: C/D frag mapping col=lane&15, row=(lane>>4)*4+reg
  const int rbase = row0 + wm * 128 + (lo << 2);
  const int cbase = col0 + wn * 64 + lr;
  #pragma unroll
  for (int mi = 0; mi < 8; ++mi) {
    #pragma unroll
    for (int ni = 0; ni < 4; ++ni) {
      #pragma unroll
      for (int r = 0; r < 4; ++r) {
        const int i = rbase + mi * 16 + r;
        const int j = cbase + ni * 16;
        const float a = acc[mi][ni][r];
        if constexpr (EPI == 0) {
          Cb[(long)bz * sCz + (long)i * ldc + j] = f2bf(a);
        } else if constexpr (EPI == 1) {
          const float xv = bf2f(Ab[(long)i * K + j]);   // K == D_ here
          Cf[((long)i * B_ + bz) * (long)D_ + j] =
              xv + vec1[bz * D_ + j] * (1.0f / S_) + scale * a;
        } else if constexpr (EPI == 2) {
          Cb[(long)i * ldc + j] = f2bf(gelu_f(a + vec1[j]));
        } else {
          const long idx = (long)i * ldc + j;
          Cf[idx] = Cf[idx] + a + vec1[j];
        }
      }
    }
  }
}

// ---------------------------------------------------------------------------
extern "C" void kernel_launch(void* const* d_in, const int* in_sizes, int n_in,
                              void* d_out, int out_size, void* d_ws, size_t ws_size,
                              hipStream_t stream) {
  (void)in_sizes; (void)n_in; (void)out_size; (void)ws_size;
  const float* x     = (const float*)d_in[0];
  const float* W_v   = (const float*)d_in[1];
  const float* theta = (const float*)d_in[2];
  const float* ln1g  = (const float*)d_in[3];
  const float* ln1b  = (const float*)d_in[4];
  const float* ln2g  = (const float*)d_in[5];
  const float* ln2b  = (const float*)d_in[6];
  const float* w1    = (const float*)d_in[7];
  const float* b1    = (const float*)d_in[8];
  const float* w2    = (const float*)d_in[9];
  const float* b2    = (const float*)d_in[10];
  float* out = (float*)d_out;

  char* ws = (char*)d_ws;
  const size_t MB = 1024ull * 1024ull;
  u16*   Wv_bf = (u16*)(ws + 0);              //  2 MB   (Th must follow contiguously)
  u16*   Th_bf = (u16*)(ws + 2 * MB);         //  2 MB
  u16*   w1_bf = (u16*)(ws + 4 * MB);         //  8 MB
  u16*   w2_bf = (u16*)(ws + 12 * MB);        //  8 MB
  float* first = (float*)(ws + 20 * MB);      // 16 KB
  u16*   Mt    = (u16*)(ws + 21 * MB);        //  8 MB  Mt[b][e][d] = M[b][d][e]
  u16*   Xn    = (u16*)(ws + 29 * MB);        // 32 MB  [B][S][D] (LN1 out, transposed)
  u16*   XWv   = (u16*)(ws + 61 * MB);        // 32 MB  (XWv,Xth contiguous: z-stride)
  u16*   Xth   = (u16*)(ws + 93 * MB);        // 32 MB
  u16*   XWvT  = (u16*)(ws + 125 * MB);       // 32 MB  [B][D][S]
  u16*   XthT  = (u16*)(ws + 157 * MB);       // 32 MB  (ends 189 MB)
  u16*   h2    = (u16*)(ws + 29 * MB);        // 32 MB  (over dead Xn)
  u16*   G     = (u16*)(ws + 61 * MB);        // 128 MB [16384][4096] (over dead XWv..XthT)

  // 1) weights -> bf16
  f2bf_k<<<dim3((D_*D_/4 + 255)/256), 256, 0, stream>>>(W_v,   Wv_bf, D_*D_/4);
  f2bf_k<<<dim3((D_*D_/4 + 255)/256), 256, 0, stream>>>(theta, Th_bf, D_*D_/4);
  f2bf_k<<<dim3((H_*D_/4 + 255)/256), 256, 0, stream>>>(w1,    w1_bf, H_*D_/4);
  f2bf_k<<<dim3((H_*D_/4 + 255)/256), 256, 0, stream>>>(w2,    w2_bf, H_*D_/4);

  // 2) LN1 + transpose to [B][S][D]
  ln_k<true><<<dim3(R_), 256, 0, stream>>>(x, Xn, ln1g, ln1b);

  // 3+4) XWv / Xth in one dispatch (z picks weight & dest; A shared = Xn)
  gemm256_k<0><<<dim3(R_/256, D_/256, 2), 512, 0, stream>>>(
      Xn, 0, Wv_bf, (long)D_*D_, D_, D_, XWv, (long)R_*D_, nullptr, nullptr, 0.f);

  // 5) first[b][d] = sum_n XWv[b][n][d]
  hipMemsetAsync(first, 0, B_ * D_ * sizeof(float), stream);
  colsum_k<<<dim3(D_/256, 16, B_), 256, 0, stream>>>(XWv, first);

  // 5b) transposes
  tr_k<<<dim3(D_/64, S_/64, B_), 256, 0, stream>>>(XWv, XWvT);
  tr_k<<<dim3(D_/64, S_/64, B_), 256, 0, stream>>>(Xth, XthT);

  // 6) Mt[b][e][d] = sum_n XWvT[b][e][n] * XthT[b][d][n]   (128-tile, K=4096)
  gemm_k<0><<<dim3(D_/128, D_/128, B_), 256, 0, stream>>>(
      XWvT, (long)D_*S_, XthT, (long)D_*S_, S_, D_, Mt, (long)D_*D_, nullptr, nullptr, 0.f);

  // 7) h = Xn + first/n + (1/(n*sqrt(D))) * Xn @ Mt^T -> d_out fp32 [S][B][D]
  gemm256_k<1><<<dim3(S_/256, D_/256, B_), 512, 0, stream>>>(
      Xn, (long)S_*D_, Mt, (long)D_*D_, D_, D_, nullptr, 0, out, first,
      1.0f / ((float)S_ * 32.0f));

  // 8) LN2: d_out -> h2 (bf16)
  ln_k<false><<<dim3(R_), 256, 0, stream>>>(out, h2, ln2g, ln2b);

  // 9) MLP, full M=16384
  gemm256_k<2><<<dim3(R_/256, H_/256, 1), 512, 0, stream>>>(
      h2, 0, w1_bf, 0, D_, H_, G, 0, nullptr, b1, 0.f);
  gemm256_k<3><<<dim3(R_/256, D_/256, 1), 512, 0, stream>>>(
      G, 0, w2_bf, 0, H_, D_, nullptr, 0, out, b2, 0.f);
}

// Round 5
// 600.048 us; speedup vs baseline: 1.7779x; 1.0118x over previous
//
#include <hip/hip_runtime.h>
#include <math.h>

// Problem dims (fixed by reference)
#define S_ 4096
#define B_ 4
#define D_ 1024
#define R_ (S_*B_)   // 16384 rows
#define H_ (4*D_)    // 4096

typedef unsigned short u16;
typedef unsigned int   u32;
typedef __attribute__((ext_vector_type(8))) short bf16x8;  // 8 bf16 in 4 VGPRs
typedef __attribute__((ext_vector_type(4))) float f32x4;

__device__ __forceinline__ u16 f2bf(float f) {
  u32 u = __float_as_uint(f);
  u32 r = (u + 0x7fffu + ((u >> 16) & 1u)) >> 16;   // RNE
  return (u16)r;
}
__device__ __forceinline__ float bf2f(u16 u) {
  return __uint_as_float(((u32)u) << 16);
}

// async global->LDS, 16B per lane; LDS dest is wave-uniform base + lane*16
__device__ __forceinline__ void gl_lds16(const u16* g, u16* l) {
  __builtin_amdgcn_global_load_lds((const __attribute__((address_space(1))) void*)g,
                                   (__attribute__((address_space(3))) void*)l,
                                   16, 0, 0);
}
// raw barrier with compiler memory fence (no implicit vmcnt drain)
__device__ __forceinline__ void BAR() {
  asm volatile("s_barrier" ::: "memory");
}

// fast GELU (tanh form): max |err| ~1e-3, far below bf16 quantum here.
__device__ __forceinline__ float gelu_f(float t) {
  const float u2 = 1.5957691216f * t + 0.0713548162726f * t * t * t;
  return t / (1.0f + __expf(-u2));
}

// ---------------------------------------------------------------------------
// fp32 -> bf16 convert (vector x4)
__global__ __launch_bounds__(256) void f2bf_k(const float* __restrict__ in,
                                              u16* __restrict__ out, int n4) {
  int i = blockIdx.x * 256 + threadIdx.x;
  if (i < n4) {
    float4 v = ((const float4*)in)[i];
    ushort4 o = make_ushort4(f2bf(v.x), f2bf(v.y), f2bf(v.z), f2bf(v.w));
    ((ushort4*)out)[i] = o;
  }
}

// ---------------------------------------------------------------------------
// LayerNorm over D=1024, one row per 256-thread block, 4 elems/thread.
// TR=true: input row r=(s*B+b) of x[S,B,D] -> output row (b*S+s)
template<bool TR>
__global__ __launch_bounds__(256) void ln_k(const float* __restrict__ x,
                                            u16* __restrict__ o,
                                            const float* __restrict__ g,
                                            const float* __restrict__ bb) {
  const int row = blockIdx.x;
  const int tid = threadIdx.x;
  const float4 v = *(const float4*)&x[(long)row * D_ + tid * 4];
  float vv[4] = {v.x, v.y, v.z, v.w};
  float s = vv[0] + vv[1] + vv[2] + vv[3];
  float q = vv[0]*vv[0] + vv[1]*vv[1] + vv[2]*vv[2] + vv[3]*vv[3];
  const int l = tid & 63, w = tid >> 6;
  #pragma unroll
  for (int off = 32; off > 0; off >>= 1) {
    s += __shfl_down(s, off, 64);
    q += __shfl_down(q, off, 64);
  }
  __shared__ float red[8];
  if (l == 0) { red[w] = s; red[4 + w] = q; }
  __syncthreads();
  s = red[0] + red[1] + red[2] + red[3];
  q = red[4] + red[5] + red[6] + red[7];
  const float m   = s * (1.0f / D_);
  const float var = q * (1.0f / D_) - m * m;
  const float inv = rsqrtf(var + 1e-5f);
  const long orow = TR ? ((long)(row % B_) * S_ + (row / B_)) : (long)row;
  const int j = tid * 4;
  ushort4 ou = make_ushort4(
      f2bf((vv[0] - m) * inv * g[j+0] + bb[j+0]),
      f2bf((vv[1] - m) * inv * g[j+1] + bb[j+1]),
      f2bf((vv[2] - m) * inv * g[j+2] + bb[j+2]),
      f2bf((vv[3] - m) * inv * g[j+3] + bb[j+3]));
  *(ushort4*)&o[orow * D_ + j] = ou;
}

// ---------------------------------------------------------------------------
// column sums of XWv: first[b][d] = sum_n XWv[b][n][d]
__global__ __launch_bounds__(256) void colsum_k(const u16* __restrict__ Xw,
                                                float* __restrict__ first) {
  const int d  = blockIdx.x * 256 + threadIdx.x;
  const int b  = blockIdx.z;
  const int n0 = blockIdx.y * 256;
  const u16* p = Xw + ((long)b * S_ + n0) * D_ + d;
  float s = 0.f;
  #pragma unroll 8
  for (int n = 0; n < 256; ++n) s += bf2f(p[(long)n * D_]);
  atomicAdd(&first[b * D_ + d], s);
}

// ---------------------------------------------------------------------------
// 64x64 bf16 transpose: in [b][S_][D_] -> out [b][D_][S_]
__global__ __launch_bounds__(256) void tr_k(const u16* __restrict__ in,
                                            u16* __restrict__ out) {
  __shared__ u16 t[64][65];
  const int b  = blockIdx.z;
  const int e0 = blockIdx.x * 64;
  const int n0 = blockIdx.y * 64;
  const int tid = threadIdx.x;
  #pragma unroll
  for (int i = 0; i < 4; ++i) {
    const int v = i * 256 + tid;
    const int r = v >> 4;            // n-offset 0..63
    const int c = (v & 15) << 2;     // e-offset
    ushort4 d4 = *(const ushort4*)&in[((long)b * S_ + n0 + r) * D_ + e0 + c];
    t[r][c+0] = d4.x; t[r][c+1] = d4.y; t[r][c+2] = d4.z; t[r][c+3] = d4.w;
  }
  __syncthreads();
  #pragma unroll
  for (int i = 0; i < 4; ++i) {
    const int v = i * 256 + tid;
    const int e = v >> 4;
    const int c = (v & 15) << 2;
    ushort4 o4 = make_ushort4(t[c+0][e], t[c+1][e], t[c+2][e], t[c+3][e]);
    *(ushort4*)&out[((long)b * D_ + e0 + e) * S_ + n0 + c] = o4;
  }
}

// ---------------------------------------------------------------------------
// 128x128-tile NT GEMM (kept for Mt: per-batch 1024x1024, K=4096).
template<int EPI>
__global__ __launch_bounds__(256, 2) void gemm_k(
    const u16* __restrict__ A, long sAz,
    const u16* __restrict__ B, long sBz,
    int K, int ldc,
    u16* __restrict__ Cb, long sCz,
    float* __restrict__ Cf,
    const float* __restrict__ vec1,
    float scale)
{
  const int bz = blockIdx.z;
  const u16* Ab = A + (long)bz * sAz;
  const u16* Bb = B + (long)bz * sBz;
  const int row0 = blockIdx.x * 128;
  const int col0 = blockIdx.y * 128;
  const int lda = K;

  __shared__ __align__(16) u16 As[128 * 32];
  __shared__ __align__(16) u16 Bs[128 * 32];

  const int tid = threadIdx.x;
  const int w = tid >> 6;
  const int l = tid & 63;
  const int wr = (w >> 1) * 64;
  const int wc = (w & 1) * 64;

  f32x4 acc[4][4];
  #pragma unroll
  for (int mi = 0; mi < 4; ++mi)
    #pragma unroll
    for (int ni = 0; ni < 4; ++ni) acc[mi][ni] = (f32x4){0.f, 0.f, 0.f, 0.f};

  const int lrow = l & 15;
  const int lo   = l >> 4;

  for (int k0 = 0; k0 < K; k0 += 32) {
    __syncthreads();
    #pragma unroll
    for (int it = 0; it < 2; ++it) {
      const int cb = it * 256 + (w << 6);
      const int c  = cb + l;
      const int r  = c >> 2;
      const int qs = ((c & 3) ^ ((r >> 1) & 3)) << 3;
      gl_lds16(Ab + (long)(row0 + r) * lda + (k0 + qs), &As[cb << 3]);
      gl_lds16(Bb + (long)(col0 + r) * lda + (k0 + qs), &Bs[cb << 3]);
    }
    __syncthreads();

    bf16x8 af[4], bfr[4];
    #pragma unroll
    for (int mi = 0; mi < 4; ++mi) {
      const int R = wr + mi * 16 + lrow;
      af[mi]  = *(const bf16x8*)&As[R * 32 + ((lo ^ ((R >> 1) & 3)) << 3)];
    }
    #pragma unroll
    for (int ni = 0; ni < 4; ++ni) {
      const int R = wc + ni * 16 + lrow;
      bfr[ni] = *(const bf16x8*)&Bs[R * 32 + ((lo ^ ((R >> 1) & 3)) << 3)];
    }
    #pragma unroll
    for (int mi = 0; mi < 4; ++mi)
      #pragma unroll
      for (int ni = 0; ni < 4; ++ni)
        acc[mi][ni] = __builtin_amdgcn_mfma_f32_16x16x32_bf16(af[mi], bfr[ni], acc[mi][ni], 0, 0, 0);
  }

  const int rbase = row0 + wr + (lo << 2);
  const int cbase = col0 + wc + lrow;
  #pragma unroll
  for (int mi = 0; mi < 4; ++mi)
    #pragma unroll
    for (int ni = 0; ni < 4; ++ni)
      #pragma unroll
      for (int r = 0; r < 4; ++r) {
        const int i = rbase + mi * 16 + r;
        const int j = cbase + ni * 16;
        if constexpr (EPI == 0)
          Cb[(long)bz * sCz + (long)i * ldc + j] = f2bf(acc[mi][ni][r]);
      }
  (void)Cf; (void)vec1; (void)scale;
}

// ---------------------------------------------------------------------------
// 256x256-tile NT GEMM, BK=64, 512 threads = 8 waves (2M x 4N).
// Deep-pipelined schedule (round-4) + NEW: LDS-repack epilogue with coalesced
// wide stores (float4 / ushort4 per lane).
template<int EPI>
__global__ __launch_bounds__(512, 2) void gemm256_k(
    const u16* __restrict__ A, long sAz,
    const u16* __restrict__ B, long sBz,
    int K, int ldc,
    u16* __restrict__ Cb, long sCz,
    float* __restrict__ Cf,
    const float* __restrict__ vec1,
    float scale)
{
  const int bz = blockIdx.z;
  const u16* Ab = A + (long)bz * sAz;
  const u16* Bb = B + (long)bz * sBz;
  const int row0 = blockIdx.x * 256;
  const int col0 = blockIdx.y * 256;

  // [dbuf][khalf][op][256*32]
  __shared__ __align__(16) u16 Lds[2][2][2][256 * 32];

  const int tid = threadIdx.x;
  const int w   = tid >> 6;       // wave 0..7
  const int l   = tid & 63;
  const int wm  = w >> 2;         // 0..1  (row half)
  const int wn  = w & 3;          // 0..3  (col quarter)
  const int lr  = l & 15;
  const int lo  = l >> 4;         // 0..3

  const int NKH = K >> 5;         // number of K-halves
  const int NT  = K >> 6;         // number of K-tiles

  // stage geometry (per load i in {0,1}): R = w*32 + i*16 + (l>>2), src chunk = (l&3)^((l>>3)&3)
  const int rs   = w * 32 + (l >> 2);
  const int qsrc = ((l & 3) ^ ((l >> 3) & 3)) << 3;   // element offset

  // read-side swizzled chunk (elements): (lo ^ ((lr>>1)&3)) * 8
  const int qsw = (lo ^ ((lr >> 1) & 3)) << 3;

  // stage one operand K-half unit
  auto STAGE = [&](int khg, int op) {
    if (khg >= NKH) return;
    const u16* src = (op ? Bb : Ab) + (long)((op ? col0 : row0) + rs) * K + khg * 32 + qsrc;
    u16* dst = &Lds[(khg >> 1) & 1][khg & 1][op][(w * 2) * 512];
    gl_lds16(src, dst);
    gl_lds16(src + (long)16 * K, dst + 512);
  };

  f32x4 acc[8][4];
  #pragma unroll
  for (int mi = 0; mi < 8; ++mi)
    #pragma unroll
    for (int ni = 0; ni < 4; ++ni) acc[mi][ni] = (f32x4){0.f, 0.f, 0.f, 0.f};

  // prologue: stage K-halves 0..2 (A,B each) = 12 loads/thread
  STAGE(0, 0); STAGE(0, 1);
  STAGE(1, 0); STAGE(1, 1);
  STAGE(2, 0); STAGE(2, 1);
  asm volatile("s_waitcnt vmcnt(8)" ::: "memory");   // A,B(0) landed
  BAR();

  for (int kt = 0; kt < NT; ++kt) {
    const u16* L00 = &Lds[kt & 1][0][0][0];  // A, kh=0
    const u16* L01 = &Lds[kt & 1][0][1][0];  // B, kh=0
    const u16* L10 = &Lds[kt & 1][1][0][0];  // A, kh=1
    const u16* L11 = &Lds[kt & 1][1][1][0];  // B, kh=1
    bf16x8 af[4], bf[4];

    // ---- phase 0: kh=0, mh=0 ----
    #pragma unroll
    for (int ni = 0; ni < 4; ++ni)
      bf[ni] = *(const bf16x8*)&L01[(wn * 64 + ni * 16 + lr) * 32 + qsw];
    #pragma unroll
    for (int mi = 0; mi < 4; ++mi)
      af[mi] = *(const bf16x8*)&L00[(wm * 128 + mi * 16 + lr) * 32 + qsw];
    STAGE(2 * kt + 3, 0);
    BAR();
    __builtin_amdgcn_s_setprio(1);
    #pragma unroll
    for (int mi = 0; mi < 4; ++mi)
      #pragma unroll
      for (int ni = 0; ni < 4; ++ni)
        acc[mi][ni] = __builtin_amdgcn_mfma_f32_16x16x32_bf16(af[mi], bf[ni], acc[mi][ni], 0, 0, 0);
    __builtin_amdgcn_s_setprio(0);
    BAR();

    // ---- phase 1: kh=0, mh=1 ----
    #pragma unroll
    for (int mi = 0; mi < 4; ++mi)
      af[mi] = *(const bf16x8*)&L00[(wm * 128 + 64 + mi * 16 + lr) * 32 + qsw];
    STAGE(2 * kt + 3, 1);
    if (kt == NT - 1) asm volatile("s_waitcnt vmcnt(0)" ::: "memory");
    else              asm volatile("s_waitcnt vmcnt(8)" ::: "memory");
    BAR();
    __builtin_amdgcn_s_setprio(1);
    #pragma unroll
    for (int mi = 0; mi < 4; ++mi)
      #pragma unroll
      for (int ni = 0; ni < 4; ++ni)
        acc[4 + mi][ni] = __builtin_amdgcn_mfma_f32_16x16x32_bf16(af[mi], bf[ni], acc[4 + mi][ni], 0, 0, 0);
    __builtin_amdgcn_s_setprio(0);
    BAR();

    // ---- phase 2: kh=1, mh=0 ----
    #pragma unroll
    for (int ni = 0; ni < 4; ++ni)
      bf[ni] = *(const bf16x8*)&L11[(wn * 64 + ni * 16 + lr) * 32 + qsw];
    #pragma unroll
    for (int mi = 0; mi < 4; ++mi)
      af[mi] = *(const bf16x8*)&L10[(wm * 128 + mi * 16 + lr) * 32 + qsw];
    STAGE(2 * kt + 4, 0);
    BAR();
    __builtin_amdgcn_s_setprio(1);
    #pragma unroll
    for (int mi = 0; mi < 4; ++mi)
      #pragma unroll
      for (int ni = 0; ni < 4; ++ni)
        acc[mi][ni] = __builtin_amdgcn_mfma_f32_16x16x32_bf16(af[mi], bf[ni], acc[mi][ni], 0, 0, 0);
    __builtin_amdgcn_s_setprio(0);
    BAR();

    // ---- phase 3: kh=1, mh=1 ----
    #pragma unroll
    for (int mi = 0; mi < 4; ++mi)
      af[mi] = *(const bf16x8*)&L10[(wm * 128 + 64 + mi * 16 + lr) * 32 + qsw];
    STAGE(2 * kt + 4, 1);
    if (kt < NT - 2)       asm volatile("s_waitcnt vmcnt(8)" ::: "memory");
    else if (kt == NT - 2) asm volatile("s_waitcnt vmcnt(4)" ::: "memory");
    else                   asm volatile("s_waitcnt vmcnt(0)" ::: "memory");
    BAR();
    __builtin_amdgcn_s_setprio(1);
    #pragma unroll
    for (int mi = 0; mi < 4; ++mi)
      #pragma unroll
      for (int ni = 0; ni < 4; ++ni)
        acc[4 + mi][ni] = __builtin_amdgcn_mfma_f32_16x16x32_bf16(af[mi], bf[ni], acc[4 + mi][ni], 0, 0, 0);
    __builtin_amdgcn_s_setprio(0);
    BAR();
  }

  // ------------------------------------------------------------------
  // Epilogue with per-wave LDS repack (coalesced wide stores).
  // acc[a][ni][r] covers wave-tile row (a>>2)*64 + (a&3)*16 + lo*4 + r,
  // col ni*16 + lr. 4 passes of 32 rows; per-wave LDS region stride 72 f32
  // (2-way bank aliasing only). After repack each lane owns 4 consecutive
  // cols of a row -> float4/ushort4 stores, 16-lane contiguous segments.
  // ------------------------------------------------------------------
  {
    float* E = (float*)(&Lds[0][0][0][0]);
    const int wbase = w * (32 * 72);
    #pragma unroll
    for (int p = 0; p < 4; ++p) {
      #pragma unroll
      for (int mh = 0; mh < 2; ++mh) {
        const int a = ((p >> 1) << 2) + ((p & 1) << 1) + mh;
        #pragma unroll
        for (int ni = 0; ni < 4; ++ni)
          #pragma unroll
          for (int r = 0; r < 4; ++r)
            E[wbase + (mh * 16 + lo * 4 + r) * 72 + ni * 16 + lr] = acc[a][ni][r];
      }
      #pragma unroll
      for (int rr = 0; rr < 8; ++rr) {
        const int rl = (l >> 4) + rr * 4;        // 0..31 within pass
        const int cl = (l & 15) * 4;             // 0..60
        const f32x4 v = *(const f32x4*)&E[wbase + rl * 72 + cl];
        const long i = row0 + wm * 128 + p * 32 + rl;
        const int  j = col0 + wn * 64 + cl;
        if constexpr (EPI == 0) {
          ushort4 o = make_ushort4(f2bf(v[0]), f2bf(v[1]), f2bf(v[2]), f2bf(v[3]));
          *(ushort4*)&Cb[(long)bz * sCz + i * ldc + j] = o;
        } else if constexpr (EPI == 1) {
          const ushort4 xv = *(const ushort4*)&Ab[i * K + j];   // K == D_ here
          const f32x4 f1 = *(const f32x4*)&vec1[bz * D_ + j];
          f32x4 o;
          o[0] = bf2f(xv.x) + f1[0] * (1.0f / S_) + scale * v[0];
          o[1] = bf2f(xv.y) + f1[1] * (1.0f / S_) + scale * v[1];
          o[2] = bf2f(xv.z) + f1[2] * (1.0f / S_) + scale * v[2];
          o[3] = bf2f(xv.w) + f1[3] * (1.0f / S_) + scale * v[3];
          *(f32x4*)&Cf[(i * B_ + bz) * (long)D_ + j] = o;
        } else if constexpr (EPI == 2) {
          const f32x4 b = *(const f32x4*)&vec1[j];
          ushort4 o = make_ushort4(f2bf(gelu_f(v[0] + b[0])),
                                   f2bf(gelu_f(v[1] + b[1])),
                                   f2bf(gelu_f(v[2] + b[2])),
                                   f2bf(gelu_f(v[3] + b[3])));
          *(ushort4*)&Cb[i * ldc + j] = o;
        } else {
          const f32x4 b = *(const f32x4*)&vec1[j];
          f32x4 c = *(const f32x4*)&Cf[i * ldc + j];
          c[0] += v[0] + b[0]; c[1] += v[1] + b[1];
          c[2] += v[2] + b[2]; c[3] += v[3] + b[3];
          *(f32x4*)&Cf[i * ldc + j] = c;
        }
      }
    }
  }
}

// ---------------------------------------------------------------------------
extern "C" void kernel_launch(void* const* d_in, const int* in_sizes, int n_in,
                              void* d_out, int out_size, void* d_ws, size_t ws_size,
                              hipStream_t stream) {
  (void)in_sizes; (void)n_in; (void)out_size; (void)ws_size;
  const float* x     = (const float*)d_in[0];
  const float* W_v   = (const float*)d_in[1];
  const float* theta = (const float*)d_in[2];
  const float* ln1g  = (const float*)d_in[3];
  const float* ln1b  = (const float*)d_in[4];
  const float* ln2g  = (const float*)d_in[5];
  const float* ln2b  = (const float*)d_in[6];
  const float* w1    = (const float*)d_in[7];
  const float* b1    = (const float*)d_in[8];
  const float* w2    = (const float*)d_in[9];
  const float* b2    = (const float*)d_in[10];
  float* out = (float*)d_out;

  char* ws = (char*)d_ws;
  const size_t MB = 1024ull * 1024ull;
  u16*   Wv_bf = (u16*)(ws + 0);              //  2 MB   (Th must follow contiguously)
  u16*   Th_bf = (u16*)(ws + 2 * MB);         //  2 MB
  u16*   w1_bf = (u16*)(ws + 4 * MB);         //  8 MB
  u16*   w2_bf = (u16*)(ws + 12 * MB);        //  8 MB
  float* first = (float*)(ws + 20 * MB);      // 16 KB
  u16*   Mt    = (u16*)(ws + 21 * MB);        //  8 MB  Mt[b][e][d] = M[b][d][e]
  u16*   Xn    = (u16*)(ws + 29 * MB);        // 32 MB  [B][S][D] (LN1 out, transposed)
  u16*   XWv   = (u16*)(ws + 61 * MB);        // 32 MB  (XWv,Xth contiguous: z-stride)
  u16*   Xth   = (u16*)(ws + 93 * MB);        // 32 MB
  u16*   XWvT  = (u16*)(ws + 125 * MB);       // 32 MB  [B][D][S]
  u16*   XthT  = (u16*)(ws + 157 * MB);       // 32 MB  (ends 189 MB)
  u16*   h2    = (u16*)(ws + 29 * MB);        // 32 MB  (over dead Xn)
  u16*   G     = (u16*)(ws + 61 * MB);        // 128 MB [16384][4096] (over dead XWv..XthT)

  // 1) weights -> bf16
  f2bf_k<<<dim3((D_*D_/4 + 255)/256), 256, 0, stream>>>(W_v,   Wv_bf, D_*D_/4);
  f2bf_k<<<dim3((D_*D_/4 + 255)/256), 256, 0, stream>>>(theta, Th_bf, D_*D_/4);
  f2bf_k<<<dim3((H_*D_/4 + 255)/256), 256, 0, stream>>>(w1,    w1_bf, H_*D_/4);
  f2bf_k<<<dim3((H_*D_/4 + 255)/256), 256, 0, stream>>>(w2,    w2_bf, H_*D_/4);

  // 2) LN1 + transpose to [B][S][D]
  ln_k<true><<<dim3(R_), 256, 0, stream>>>(x, Xn, ln1g, ln1b);

  // 3+4) XWv / Xth in one dispatch (z picks weight & dest; A shared = Xn)
  gemm256_k<0><<<dim3(R_/256, D_/256, 2), 512, 0, stream>>>(
      Xn, 0, Wv_bf, (long)D_*D_, D_, D_, XWv, (long)R_*D_, nullptr, nullptr, 0.f);

  // 5) first[b][d] = sum_n XWv[b][n][d]
  hipMemsetAsync(first, 0, B_ * D_ * sizeof(float), stream);
  colsum_k<<<dim3(D_/256, 16, B_), 256, 0, stream>>>(XWv, first);

  // 5b) transposes
  tr_k<<<dim3(D_/64, S_/64, B_), 256, 0, stream>>>(XWv, XWvT);
  tr_k<<<dim3(D_/64, S_/64, B_), 256, 0, stream>>>(Xth, XthT);

  // 6) Mt[b][e][d] = sum_n XWvT[b][e][n] * XthT[b][d][n]   (128-tile, K=4096)
  gemm_k<0><<<dim3(D_/128, D_/128, B_), 256, 0, stream>>>(
      XWvT, (long)D_*S_, XthT, (long)D_*S_, S_, D_, Mt, (long)D_*D_, nullptr, nullptr, 0.f);

  // 7) h = Xn + first/n + (1/(n*sqrt(D))) * Xn @ Mt^T -> d_out fp32 [S][B][D]
  gemm256_k<1><<<dim3(S_/256, D_/256, B_), 512, 0, stream>>>(
      Xn, (long)S_*D_, Mt, (long)D_*D_, D_, D_, nullptr, 0, out, first,
      1.0f / ((float)S_ * 32.0f));

  // 8) LN2: d_out -> h2 (bf16)
  ln_k<false><<<dim3(R_), 256, 0, stream>>>(out, h2, ln2g, ln2b);

  // 9) MLP, full M=16384
  gemm256_k<2><<<dim3(R_/256, H_/256, 1), 512, 0, stream>>>(
      h2, 0, w1_bf, 0, D_, H_, G, 0, nullptr, b1, 0.f);
  gemm256_k<3><<<dim3(R_/256, D_/256, 1), 512, 0, stream>>>(
      G, 0, w2_bf, 0, H_, D_, nullptr, 0, out, b2, 0.f);
}